// Round 1
// baseline (2470.102 us; speedup 1.0000x reference)
//
#include <hip/hip_runtime.h>
#include <hip/hip_bf16.h>

// Problem constants
static constexpr int B   = 4;
static constexpr int N   = 16384;
static constexpr int E   = 131072;
static constexpr int C   = 128;
static constexpr int ND  = 3;
static constexpr int MID = 128;
static constexpr int OUT = 128;
static constexpr int K1  = C * ND;   // 384
static constexpr int NPB = 8;        // nodes per block in MLP

// ---------------- prep: weight relayout + Sigma = L L^T ----------------
__global__ void k_prep(const float* __restrict__ W1, const float* __restrict__ W2,
                       const float* __restrict__ L, float* __restrict__ W1c,
                       float* __restrict__ W2c, float* __restrict__ Sig) {
    int m = threadIdx.x;  // 0..127
    // W1c[k4][m][u] = W1[m][k4*4+u]  -> thread m loads float4 coalesced in MLP
    for (int k = 0; k < K1; ++k)
        W1c[(k >> 2) * (MID * 4) + m * 4 + (k & 3)] = W1[m * K1 + k];
    for (int k = 0; k < MID; ++k)
        W2c[(k >> 2) * (OUT * 4) + m * 4 + (k & 3)] = W2[m * MID + k];
    if (m < 9) {
        int i = m / 3, j = m % 3;
        Sig[m] = L[i * 3 + 0] * L[j * 3 + 0] + L[i * 3 + 1] * L[j * 3 + 1] +
                 L[i * 3 + 2] * L[j * 3 + 2];
    }
}

// ---------------- transpose f (B,C,N) -> fT (B,N,C) ----------------
__global__ void k_transpose(const float* __restrict__ f, float* __restrict__ fT) {
    __shared__ float tile[32][33];
    int b = blockIdx.z;
    int n0 = blockIdx.x * 32, c0 = blockIdx.y * 32;
    const float* fb = f + (size_t)b * C * N;
    float* fTb = fT + (size_t)b * N * C;
    int tx = threadIdx.x, ty = threadIdx.y;  // (32,8)
    #pragma unroll
    for (int i = 0; i < 32; i += 8)
        tile[ty + i][tx] = fb[(size_t)(c0 + ty + i) * N + n0 + tx];
    __syncthreads();
    #pragma unroll
    for (int i = 0; i < 32; i += 8)
        fTb[(size_t)(n0 + ty + i) * C + c0 + tx] = tile[tx][ty + i];
}

// ---------------- gradient scatter: grad[b, tgt, c*3+d] += (f[src,c]-f[tgt,c])*egw[e,d] ----------------
__global__ __launch_bounds__(128) void k_scatter_grad(const float* __restrict__ fT,
                                                      const int* __restrict__ ei,
                                                      const float* __restrict__ egw,
                                                      float* __restrict__ grad) {
    int be = blockIdx.x;                 // 0 .. B*E-1
    int b = be / E, e = be % E;
    const int* ep = ei + ((size_t)b * E + e) * 2;
    int src = ep[0], tgt = ep[1];
    int c = threadIdx.x;                 // 0..127
    const float* fb = fT + (size_t)b * N * C;
    float df = fb[(size_t)src * C + c] - fb[(size_t)tgt * C + c];
    const float* w = egw + ((size_t)b * E + e) * ND;
    float w0 = w[0], w1 = w[1], w2 = w[2];
    float* gd = grad + ((size_t)b * N + tgt) * K1 + c * 3;
    atomicAdd(gd + 0, df * w0);
    atomicAdd(gd + 1, df * w1);
    atomicAdd(gd + 2, df * w2);
}

// ---------------- MLP: fo = W2 @ gelu(W1 @ g + b1) + b2, per node ----------------
__global__ __launch_bounds__(128) void k_mlp(const float* __restrict__ grad,
                                             const float* __restrict__ W1c,
                                             const float* __restrict__ b1,
                                             const float* __restrict__ W2c,
                                             const float* __restrict__ b2,
                                             float* __restrict__ fo) {
    __shared__ float g_s[NPB][K1];   // 12 KB
    __shared__ float h_s[NPB][MID];  // 4 KB
    size_t n0 = (size_t)blockIdx.x * NPB;  // flat node index over B*N
    int m = threadIdx.x;                   // 0..127
    const float* gsrc = grad + n0 * K1;
    for (int i = m; i < NPB * K1; i += 128) g_s[i / K1][i % K1] = gsrc[i];
    __syncthreads();

    float acc[NPB];
    float bb = b1[m];
    #pragma unroll
    for (int j = 0; j < NPB; ++j) acc[j] = bb;
    for (int k4 = 0; k4 < K1 / 4; ++k4) {
        float4 w = *(const float4*)(W1c + k4 * (MID * 4) + m * 4);
        #pragma unroll
        for (int j = 0; j < NPB; ++j) {
            float4 g = *(const float4*)(&g_s[j][k4 * 4]);
            acc[j] += w.x * g.x + w.y * g.y + w.z * g.z + w.w * g.w;
        }
    }
    #pragma unroll
    for (int j = 0; j < NPB; ++j) {
        float x = acc[j];
        h_s[j][m] = 0.5f * x * (1.0f + erff(x * 0.70710678118654752f));
    }
    __syncthreads();

    float acc2[NPB];
    float bb2 = b2[m];
    #pragma unroll
    for (int j = 0; j < NPB; ++j) acc2[j] = bb2;
    for (int k4 = 0; k4 < MID / 4; ++k4) {
        float4 w = *(const float4*)(W2c + k4 * (OUT * 4) + m * 4);
        #pragma unroll
        for (int j = 0; j < NPB; ++j) {
            float4 h4 = *(const float4*)(&h_s[j][k4 * 4]);
            acc2[j] += w.x * h4.x + w.y * h4.y + w.z * h4.z + w.w * h4.w;
        }
    }
    #pragma unroll
    for (int j = 0; j < NPB; ++j) fo[(n0 + j) * OUT + m] = acc2[j];
}

// ---------------- edge aggregation: Gaussian kernel + scatter-add ----------------
__global__ __launch_bounds__(128) void k_edge_agg(const float* __restrict__ fo,
                                                  const float* __restrict__ nodes,
                                                  const float* __restrict__ nw,
                                                  const int* __restrict__ ei,
                                                  const float* __restrict__ Sig,
                                                  const float* __restrict__ cb,
                                                  float* __restrict__ outacc,
                                                  float* __restrict__ denom) {
    int be = blockIdx.x;
    int b = be / E, e = be % E;
    const int* ep = ei + ((size_t)b * E + e) * 2;
    int src = ep[0], tgt = ep[1];
    int c = threadIdx.x;
    const float* ns = nodes + ((size_t)b * N + src) * ND;
    const float* nt = nodes + ((size_t)b * N + tgt) * ND;
    float d0 = ns[0] - nt[0], d1 = ns[1] - nt[1], d2 = ns[2] - nt[2];
    float q = d0 * (Sig[0] * d0 + Sig[1] * d1 + Sig[2] * d2) +
              d1 * (Sig[3] * d0 + Sig[4] * d1 + Sig[5] * d2) +
              d2 * (Sig[6] * d0 + Sig[7] * d1 + Sig[8] * d2) +
              d0 * cb[0] + d1 * cb[1] + d2 * cb[2];
    float kern = nw[(size_t)b * N + src] * expf(-q);
    float v = fo[((size_t)b * N + src) * OUT + c] * kern;
    atomicAdd(&outacc[((size_t)b * N + tgt) * OUT + c], v);
    if (c == 0) atomicAdd(&denom[(size_t)b * N + tgt], kern);
}

// ---------------- finalize: self edge + normalize + transpose to (B,OUT,N) ----------------
__global__ __launch_bounds__(256) void k_finalize(const float* __restrict__ outacc,
                                                  const float* __restrict__ fo,
                                                  const float* __restrict__ nw,
                                                  const float* __restrict__ denom,
                                                  float* __restrict__ out) {
    __shared__ float t[OUT][65];  // 65 pad: conflict-free transposed writes
    int b = blockIdx.y;
    int n0 = blockIdx.x * 64;
    int tid = threadIdx.x;  // 256
    #pragma unroll
    for (int i = 0; i < 32; ++i) {
        int idx = tid + i * 256;          // 0..8191
        int nl = idx >> 7, o = idx & 127; // o fastest -> coalesced reads
        size_t n = (size_t)b * N + n0 + nl;
        float w = nw[n];
        float den = denom[n] + w;         // + self-edge kernel (d=0 -> exp(0)=1)
        float val = (outacc[n * OUT + o] + fo[n * OUT + o] * w) / den;
        t[o][nl] = val;
    }
    __syncthreads();
    #pragma unroll
    for (int i = 0; i < 32; ++i) {
        int idx = tid + i * 256;
        int o = idx >> 6, nl = idx & 63;  // nl fastest -> coalesced writes
        out[((size_t)b * OUT + o) * N + n0 + nl] = t[o][nl];
    }
}

extern "C" void kernel_launch(void* const* d_in, const int* in_sizes, int n_in,
                              void* d_out, int out_size, void* d_ws, size_t ws_size,
                              hipStream_t stream) {
    const float* f     = (const float*)d_in[0];
    const float* nodes = (const float*)d_in[1];
    const float* nw    = (const float*)d_in[2];
    const int*   ei    = (const int*)d_in[3];
    const float* egw   = (const float*)d_in[4];
    const float* W1    = (const float*)d_in[5];
    const float* b1    = (const float*)d_in[6];
    const float* W2    = (const float*)d_in[7];
    const float* b2    = (const float*)d_in[8];
    const float* L     = (const float*)d_in[9];
    const float* cb    = (const float*)d_in[10];
    float* out = (float*)d_out;

    // Workspace layout (region reuse):
    //   region A: fT (B*N*C f32) -> reused as fo after k_mlp overwrites it
    //   region B: grad (B*N*384 f32) -> reused as outacc + denom after k_mlp
    char* ws = (char*)d_ws;
    float* regA = (float*)ws;                       ws += (size_t)B * N * C * 4;
    float* regB = (float*)ws;                       ws += (size_t)B * N * K1 * 4;
    float* W1c  = (float*)ws;                       ws += (size_t)MID * K1 * 4;
    float* W2c  = (float*)ws;                       ws += (size_t)OUT * MID * 4;
    float* Sig  = (float*)ws;                       ws += 16 * 4;

    float* fT     = regA;
    float* fo     = regA;                 // alias: valid, fT dead after scatter
    float* grad   = regB;
    float* outacc = regB;                 // alias: valid, grad dead after mlp
    float* denom  = regB + (size_t)B * N * OUT;

    hipMemsetAsync(grad, 0, (size_t)B * N * K1 * 4, stream);
    k_prep<<<1, 128, 0, stream>>>(W1, W2, L, W1c, W2c, Sig);
    k_transpose<<<dim3(N / 32, C / 32, B), dim3(32, 8), 0, stream>>>(f, fT);
    k_scatter_grad<<<B * E, 128, 0, stream>>>(fT, ei, egw, grad);
    k_mlp<<<(B * N) / NPB, 128, 0, stream>>>(grad, W1c, b1, W2c, b2, fo);
    hipMemsetAsync(outacc, 0, (size_t)B * N * OUT * 4, stream);
    hipMemsetAsync(denom, 0, (size_t)B * N * 4, stream);
    k_edge_agg<<<B * E, 128, 0, stream>>>(fo, nodes, nw, ei, Sig, cb, outacc, denom);
    k_finalize<<<dim3(N / 64, B), 256, 0, stream>>>(outacc, fo, nw, denom, out);
}

// Round 2
// 597.131 us; speedup vs baseline: 4.1366x; 4.1366x over previous
//
#include <hip/hip_runtime.h>
#include <hip/hip_bf16.h>

// Problem constants
static constexpr int B   = 4;
static constexpr int N   = 16384;   // 2^14
static constexpr int E   = 131072;  // 2^17
static constexpr int C   = 128;
static constexpr int ND  = 3;
static constexpr int MID = 128;
static constexpr int OUT = 128;
static constexpr int K1  = C * ND;  // 384
static constexpr int NPB = 16;      // nodes per block in fused grad+MLP

// ---------------- prep: weight relayout + Sigma = L L^T ----------------
__global__ void k_prep(const float* __restrict__ W1, const float* __restrict__ W2,
                       const float* __restrict__ L, float* __restrict__ W1c,
                       float* __restrict__ W2c, float* __restrict__ Sig) {
    int m = threadIdx.x;  // 0..127
    for (int k = 0; k < K1; ++k)
        W1c[(k >> 2) * (MID * 4) + m * 4 + (k & 3)] = W1[m * K1 + k];
    for (int k = 0; k < MID; ++k)
        W2c[(k >> 2) * (OUT * 4) + m * 4 + (k & 3)] = W2[m * MID + k];
    if (m < 9) {
        int i = m / 3, j = m % 3;
        Sig[m] = L[i * 3 + 0] * L[j * 3 + 0] + L[i * 3 + 1] * L[j * 3 + 1] +
                 L[i * 3 + 2] * L[j * 3 + 2];
    }
}

// ---------------- transpose f (B,C,N) -> fT (B,N,C) ----------------
__global__ void k_transpose(const float* __restrict__ f, float* __restrict__ fT) {
    __shared__ float tile[32][33];
    int b = blockIdx.z;
    int n0 = blockIdx.x * 32, c0 = blockIdx.y * 32;
    const float* fb = f + (size_t)b * C * N;
    float* fTb = fT + (size_t)b * N * C;
    int tx = threadIdx.x, ty = threadIdx.y;  // (32,8)
    #pragma unroll
    for (int i = 0; i < 32; i += 8)
        tile[ty + i][tx] = fb[(size_t)(c0 + ty + i) * N + n0 + tx];
    __syncthreads();
    #pragma unroll
    for (int i = 0; i < 32; i += 8)
        fTb[(size_t)(n0 + ty + i) * C + c0 + tx] = tile[tx][ty + i];
}

// ---------------- CSR build: count degrees by target ----------------
__global__ void k_count(const int* __restrict__ ei, int* __restrict__ deg) {
    int idx = blockIdx.x * 256 + threadIdx.x;  // 0..B*E-1
    if (idx >= B * E) return;
    int b = idx >> 17;  // idx / E
    int tgt = ei[(size_t)idx * 2 + 1];
    atomicAdd(&deg[b * N + tgt], 1);
}

// ---------------- exclusive scan over B*N = 65536 counters (single block) ----------------
__global__ __launch_bounds__(1024) void k_scan(const int* __restrict__ deg,
                                               int* __restrict__ rowptr) {
    __shared__ int s[1024];
    int t = threadIdx.x;
    int base = t * 64;
    int sum = 0;
    for (int i = 0; i < 64; ++i) sum += deg[base + i];
    s[t] = sum;
    __syncthreads();
    for (int d = 1; d < 1024; d <<= 1) {
        int v = s[t];
        int u = (t >= d) ? s[t - d] : 0;
        __syncthreads();
        s[t] = v + u;
        __syncthreads();
    }
    int run = (t == 0) ? 0 : s[t - 1];
    for (int i = 0; i < 64; ++i) { rowptr[base + i] = run; run += deg[base + i]; }
    if (t == 1023) rowptr[B * N] = run;
}

// ---------------- CSR fill: edge id pack + precompute Gaussian kernel weight ----------------
__global__ void k_fill(const int* __restrict__ ei, const float* __restrict__ nodes,
                       const float* __restrict__ nw, const float* __restrict__ Sig,
                       const float* __restrict__ cb, const int* __restrict__ rowptr,
                       int* __restrict__ cursor, int* __restrict__ packA,
                       float* __restrict__ karr) {
    int idx = blockIdx.x * 256 + threadIdx.x;  // 0..B*E-1
    if (idx >= B * E) return;
    int b = idx >> 17;
    int e = idx & (E - 1);
    int src = ei[(size_t)idx * 2], tgt = ei[(size_t)idx * 2 + 1];
    int bn = b * N + tgt;
    int pos = atomicAdd(&cursor[bn], 1);
    int o = rowptr[bn] + pos;
    packA[o] = (e << 14) | src;  // e:17 bits, src:14 bits -> 31 bits, positive int
    const float* ns = nodes + ((size_t)b * N + src) * ND;
    const float* nt = nodes + (size_t)bn * ND;
    float d0 = ns[0] - nt[0], d1 = ns[1] - nt[1], d2 = ns[2] - nt[2];
    float q = d0 * (Sig[0] * d0 + Sig[1] * d1 + Sig[2] * d2) +
              d1 * (Sig[3] * d0 + Sig[4] * d1 + Sig[5] * d2) +
              d2 * (Sig[6] * d0 + Sig[7] * d1 + Sig[8] * d2) +
              d0 * cb[0] + d1 * cb[1] + d2 * cb[2];
    karr[o] = nw[(size_t)b * N + src] * expf(-q);
}

// ---------------- fused gradient gather + pointwise MLP ----------------
// Per block: NPB nodes. Gradient accumulated in registers via CSR gather (no
// atomics, no grad buffer in HBM), staged to LDS, then the 384->128->GELU->128
// MLP runs in-block with weight reuse across NPB nodes.
__global__ __launch_bounds__(128) void k_grad_mlp(const float* __restrict__ fT,
                                                  const int* __restrict__ rowptr,
                                                  const int* __restrict__ packA,
                                                  const float* __restrict__ egw,
                                                  const float* __restrict__ W1c,
                                                  const float* __restrict__ b1,
                                                  const float* __restrict__ W2c,
                                                  const float* __restrict__ b2,
                                                  float* __restrict__ fo) {
    __shared__ float g_s[NPB][K1];   // 24 KB
    __shared__ float h_s[NPB][MID];  // 8 KB
    int c = threadIdx.x;             // 0..127 channel
    int n0 = blockIdx.x * NPB;       // flat node over B*N

    for (int j = 0; j < NPB; ++j) {
        int n = n0 + j;
        int b = n >> 14;                      // N = 2^14
        size_t bbase = (size_t)b * N;
        float ftgt = fT[((size_t)n) * C + c];
        int base = rowptr[n], cnt = rowptr[n + 1] - base;
        float a0 = 0.f, a1 = 0.f, a2 = 0.f;
        for (int i = 0; i < cnt; ++i) {
            int pk = packA[base + i];
            int src = pk & (N - 1);
            int e = pk >> 14;
            const float* w = egw + ((size_t)b * E + e) * ND;
            float w0 = w[0], w1 = w[1], w2 = w[2];
            float df = fT[(bbase + src) * C + c] - ftgt;
            a0 += df * w0; a1 += df * w1; a2 += df * w2;
        }
        g_s[j][c * 3 + 0] = a0;
        g_s[j][c * 3 + 1] = a1;
        g_s[j][c * 3 + 2] = a2;
    }
    __syncthreads();

    int m = c;
    float acc[NPB];
    float bb = b1[m];
    #pragma unroll
    for (int j = 0; j < NPB; ++j) acc[j] = bb;
    for (int k4 = 0; k4 < K1 / 4; ++k4) {
        float4 w = *(const float4*)(W1c + k4 * (MID * 4) + m * 4);
        #pragma unroll
        for (int j = 0; j < NPB; ++j) {
            float4 g = *(const float4*)(&g_s[j][k4 * 4]);
            acc[j] += w.x * g.x + w.y * g.y + w.z * g.z + w.w * g.w;
        }
    }
    #pragma unroll
    for (int j = 0; j < NPB; ++j) {
        float x = acc[j];
        h_s[j][m] = 0.5f * x * (1.0f + erff(x * 0.70710678118654752f));
    }
    __syncthreads();

    float acc2[NPB];
    float bb2 = b2[m];
    #pragma unroll
    for (int j = 0; j < NPB; ++j) acc2[j] = bb2;
    for (int k4 = 0; k4 < MID / 4; ++k4) {
        float4 w = *(const float4*)(W2c + k4 * (OUT * 4) + m * 4);
        #pragma unroll
        for (int j = 0; j < NPB; ++j) {
            float4 h4 = *(const float4*)(&h_s[j][k4 * 4]);
            acc2[j] += w.x * h4.x + w.y * h4.y + w.z * h4.z + w.w * h4.w;
        }
    }
    #pragma unroll
    for (int j = 0; j < NPB; ++j) fo[((size_t)n0 + j) * OUT + m] = acc2[j];
}

// ---------------- edge aggregation via CSR gather (no atomics) + normalize ----------------
__global__ __launch_bounds__(128) void k_agg(const float* __restrict__ fo,
                                             const float* __restrict__ nw,
                                             const int* __restrict__ rowptr,
                                             const int* __restrict__ packA,
                                             const float* __restrict__ karr,
                                             float* __restrict__ tmp) {
    int n = blockIdx.x;   // flat node over B*N
    int c = threadIdx.x;  // 0..127
    size_t bbase = (size_t)(n >> 14) * N;
    int base = rowptr[n], cnt = rowptr[n + 1] - base;
    float o = 0.f, den = 0.f;
    for (int i = 0; i < cnt; ++i) {
        float kern = karr[base + i];
        int src = packA[base + i] & (N - 1);
        o += fo[(bbase + src) * OUT + c] * kern;
        den += kern;
    }
    float wn = nw[n];                       // self edge: d=0 -> kern = nw[n]
    float fn = fo[(size_t)n * OUT + c];
    tmp[(size_t)n * OUT + c] = (o + fn * wn) / (den + wn);
}

// ---------------- output transpose (B,N,OUT) -> (B,OUT,N) ----------------
__global__ __launch_bounds__(256) void k_out_t(const float* __restrict__ tmp,
                                               float* __restrict__ out) {
    __shared__ float t[OUT][65];
    int b = blockIdx.y;
    int n0 = blockIdx.x * 64;
    int tid = threadIdx.x;  // 256
    #pragma unroll
    for (int i = 0; i < 32; ++i) {
        int idx = tid + i * 256;           // 0..8191
        int nl = idx >> 7, o = idx & 127;  // o fastest -> coalesced reads
        t[o][nl] = tmp[(((size_t)b * N + n0 + nl)) * OUT + o];
    }
    __syncthreads();
    #pragma unroll
    for (int i = 0; i < 32; ++i) {
        int idx = tid + i * 256;
        int o = idx >> 6, nl = idx & 63;   // nl fastest -> coalesced writes
        out[((size_t)b * OUT + o) * N + n0 + nl] = t[o][nl];
    }
}

extern "C" void kernel_launch(void* const* d_in, const int* in_sizes, int n_in,
                              void* d_out, int out_size, void* d_ws, size_t ws_size,
                              hipStream_t stream) {
    const float* f     = (const float*)d_in[0];
    const float* nodes = (const float*)d_in[1];
    const float* nw    = (const float*)d_in[2];
    const int*   ei    = (const int*)d_in[3];
    const float* egw   = (const float*)d_in[4];
    const float* W1    = (const float*)d_in[5];
    const float* b1    = (const float*)d_in[6];
    const float* W2    = (const float*)d_in[7];
    const float* b2    = (const float*)d_in[8];
    const float* L     = (const float*)d_in[9];
    const float* cb    = (const float*)d_in[10];
    float* out = (float*)d_out;

    char* ws = (char*)d_ws;
    auto alloc = [&](size_t bytes) {
        void* p = ws;
        ws += (bytes + 255) & ~(size_t)255;
        return p;
    };
    float* fT     = (float*)alloc((size_t)B * N * C * 4);
    float* fo     = (float*)alloc((size_t)B * N * OUT * 4);
    float* tmp    = (float*)alloc((size_t)B * N * OUT * 4);
    float* W1c    = (float*)alloc((size_t)MID * K1 * 4);
    float* W2c    = (float*)alloc((size_t)OUT * MID * 4);
    float* Sig    = (float*)alloc(16 * 4);
    int*   deg    = (int*)alloc((size_t)B * N * 4);
    int*   cursor = (int*)alloc((size_t)B * N * 4);
    int*   rowptr = (int*)alloc(((size_t)B * N + 1) * 4);
    int*   packA  = (int*)alloc((size_t)B * E * 4);
    float* karr   = (float*)alloc((size_t)B * E * 4);

    hipMemsetAsync(deg, 0, (size_t)B * N * 4, stream);
    hipMemsetAsync(cursor, 0, (size_t)B * N * 4, stream);

    k_prep<<<1, 128, 0, stream>>>(W1, W2, L, W1c, W2c, Sig);
    k_transpose<<<dim3(N / 32, C / 32, B), dim3(32, 8), 0, stream>>>(f, fT);
    k_count<<<(B * E) / 256, 256, 0, stream>>>(ei, deg);
    k_scan<<<1, 1024, 0, stream>>>(deg, rowptr);
    k_fill<<<(B * E) / 256, 256, 0, stream>>>(ei, nodes, nw, Sig, cb, rowptr,
                                              cursor, packA, karr);
    k_grad_mlp<<<(B * N) / NPB, 128, 0, stream>>>(fT, rowptr, packA, egw, W1c, b1,
                                                  W2c, b2, fo);
    k_agg<<<B * N, 128, 0, stream>>>(fo, nw, rowptr, packA, karr, tmp);
    k_out_t<<<dim3(N / 64, B), 256, 0, stream>>>(tmp, out);
}

// Round 3
// 388.233 us; speedup vs baseline: 6.3624x; 1.5381x over previous
//
#include <hip/hip_runtime.h>
#include <hip/hip_bf16.h>

// Problem constants
static constexpr int B   = 4;
static constexpr int N   = 16384;   // 2^14
static constexpr int E   = 131072;  // 2^17
static constexpr int C   = 128;
static constexpr int ND  = 3;
static constexpr int MID = 128;
static constexpr int OUT = 128;
static constexpr int K1  = C * ND;  // 384
static constexpr int NPB = 16;      // nodes per block in fused grad+MLP

// ---------------- prep: weight relayout + Sigma = L L^T ----------------
__global__ void k_prep(const float* __restrict__ W1, const float* __restrict__ W2,
                       const float* __restrict__ L, float* __restrict__ W1c,
                       float* __restrict__ W2c, float* __restrict__ Sig) {
    int m = threadIdx.x;  // 0..127
    for (int k = 0; k < K1; ++k)
        W1c[(k >> 2) * (MID * 4) + m * 4 + (k & 3)] = W1[m * K1 + k];
    for (int k = 0; k < MID; ++k)
        W2c[(k >> 2) * (OUT * 4) + m * 4 + (k & 3)] = W2[m * MID + k];
    if (m < 9) {
        int i = m / 3, j = m % 3;
        Sig[m] = L[i * 3 + 0] * L[j * 3 + 0] + L[i * 3 + 1] * L[j * 3 + 1] +
                 L[i * 3 + 2] * L[j * 3 + 2];
    }
}

// ---------------- transpose f (B,C,N) -> fT (B,N,C) ----------------
__global__ void k_transpose(const float* __restrict__ f, float* __restrict__ fT) {
    __shared__ float tile[32][33];
    int b = blockIdx.z;
    int n0 = blockIdx.x * 32, c0 = blockIdx.y * 32;
    const float* fb = f + (size_t)b * C * N;
    float* fTb = fT + (size_t)b * N * C;
    int tx = threadIdx.x, ty = threadIdx.y;  // (32,8)
    #pragma unroll
    for (int i = 0; i < 32; i += 8)
        tile[ty + i][tx] = fb[(size_t)(c0 + ty + i) * N + n0 + tx];
    __syncthreads();
    #pragma unroll
    for (int i = 0; i < 32; i += 8)
        fTb[(size_t)(n0 + ty + i) * C + c0 + tx] = tile[tx][ty + i];
}

// ---------------- CSR build: count degrees by target ----------------
__global__ void k_count(const int* __restrict__ ei, int* __restrict__ deg) {
    int idx = blockIdx.x * 256 + threadIdx.x;  // 0..B*E-1
    if (idx >= B * E) return;
    int b = idx >> 17;  // idx / E
    int tgt = ei[(size_t)idx * 2 + 1];
    atomicAdd(&deg[b * N + tgt], 1);
}

// ---------------- exclusive scan over B*N = 65536 counters (single block) ----------------
__global__ __launch_bounds__(1024) void k_scan(const int* __restrict__ deg,
                                               int* __restrict__ rowptr) {
    __shared__ int s[1024];
    int t = threadIdx.x;
    int base = t * 64;
    int sum = 0;
    for (int i = 0; i < 64; ++i) sum += deg[base + i];
    s[t] = sum;
    __syncthreads();
    for (int d = 1; d < 1024; d <<= 1) {
        int v = s[t];
        int u = (t >= d) ? s[t - d] : 0;
        __syncthreads();
        s[t] = v + u;
        __syncthreads();
    }
    int run = (t == 0) ? 0 : s[t - 1];
    for (int i = 0; i < 64; ++i) { rowptr[base + i] = run; run += deg[base + i]; }
    if (t == 1023) rowptr[B * N] = run;
}

// ---------------- CSR fill: src index, CSR-ordered edge weights, Gaussian kernel ----------------
__global__ void k_fill(const int* __restrict__ ei, const float* __restrict__ egw,
                       const float* __restrict__ nodes, const float* __restrict__ nw,
                       const float* __restrict__ Sig, const float* __restrict__ cb,
                       const int* __restrict__ rowptr, int* __restrict__ cursor,
                       int* __restrict__ packA, float4* __restrict__ egwp,
                       float* __restrict__ karr) {
    int idx = blockIdx.x * 256 + threadIdx.x;  // 0..B*E-1
    if (idx >= B * E) return;
    int b = idx >> 17;
    int src = ei[(size_t)idx * 2], tgt = ei[(size_t)idx * 2 + 1];
    int bn = b * N + tgt;
    int pos = atomicAdd(&cursor[bn], 1);
    int o = rowptr[bn] + pos;
    packA[o] = src;
    const float* w = egw + (size_t)idx * ND;
    egwp[o] = make_float4(w[0], w[1], w[2], 0.f);
    const float* ns = nodes + ((size_t)b * N + src) * ND;
    const float* nt = nodes + (size_t)bn * ND;
    float d0 = ns[0] - nt[0], d1 = ns[1] - nt[1], d2 = ns[2] - nt[2];
    float q = d0 * (Sig[0] * d0 + Sig[1] * d1 + Sig[2] * d2) +
              d1 * (Sig[3] * d0 + Sig[4] * d1 + Sig[5] * d2) +
              d2 * (Sig[6] * d0 + Sig[7] * d1 + Sig[8] * d2) +
              d0 * cb[0] + d1 * cb[1] + d2 * cb[2];
    karr[o] = nw[(size_t)b * N + src] * expf(-q);
}

// ---------------- fused gradient gather + pointwise MLP ----------------
// Gather: slot s = tid>>5 handles node jj+s; lane cg = tid&31 handles 4
// channels (float4); 2-edge unroll; no indirection (egwp is CSR-ordered).
__global__ __launch_bounds__(128) void k_grad_mlp(const float* __restrict__ fT,
                                                  const int* __restrict__ rowptr,
                                                  const int* __restrict__ packA,
                                                  const float4* __restrict__ egwp,
                                                  const float* __restrict__ W1c,
                                                  const float* __restrict__ b1,
                                                  const float* __restrict__ W2c,
                                                  const float* __restrict__ b2,
                                                  float* __restrict__ fo) {
    __shared__ float g_s[NPB][K1];  // 24 KB; reused for h after layer 1
    int tid = threadIdx.x;
    int cg = tid & 31;
    int s  = tid >> 5;
    int cg4 = cg * 4;
    int n0 = blockIdx.x * NPB;

    for (int jj = 0; jj < NPB; jj += 4) {
        int j = jj + s;
        int n = n0 + j;
        size_t bbase = (size_t)(n >> 14) * N;
        float4 ftgt = *(const float4*)(fT + (size_t)n * C + cg4);
        int base = rowptr[n], cnt = rowptr[n + 1] - base;
        float4 a0 = make_float4(0.f, 0.f, 0.f, 0.f);
        float4 a1 = a0, a2 = a0;
        int i = 0;
        for (; i + 2 <= cnt; i += 2) {
            int src0 = packA[base + i];
            int src1 = packA[base + i + 1];
            float4 w0 = egwp[base + i];
            float4 w1 = egwp[base + i + 1];
            float4 fs0 = *(const float4*)(fT + (bbase + src0) * C + cg4);
            float4 fs1 = *(const float4*)(fT + (bbase + src1) * C + cg4);
            float dx = fs0.x - ftgt.x, dy = fs0.y - ftgt.y,
                  dz = fs0.z - ftgt.z, dw = fs0.w - ftgt.w;
            a0.x = fmaf(dx, w0.x, a0.x); a0.y = fmaf(dy, w0.x, a0.y);
            a0.z = fmaf(dz, w0.x, a0.z); a0.w = fmaf(dw, w0.x, a0.w);
            a1.x = fmaf(dx, w0.y, a1.x); a1.y = fmaf(dy, w0.y, a1.y);
            a1.z = fmaf(dz, w0.y, a1.z); a1.w = fmaf(dw, w0.y, a1.w);
            a2.x = fmaf(dx, w0.z, a2.x); a2.y = fmaf(dy, w0.z, a2.y);
            a2.z = fmaf(dz, w0.z, a2.z); a2.w = fmaf(dw, w0.z, a2.w);
            dx = fs1.x - ftgt.x; dy = fs1.y - ftgt.y;
            dz = fs1.z - ftgt.z; dw = fs1.w - ftgt.w;
            a0.x = fmaf(dx, w1.x, a0.x); a0.y = fmaf(dy, w1.x, a0.y);
            a0.z = fmaf(dz, w1.x, a0.z); a0.w = fmaf(dw, w1.x, a0.w);
            a1.x = fmaf(dx, w1.y, a1.x); a1.y = fmaf(dy, w1.y, a1.y);
            a1.z = fmaf(dz, w1.y, a1.z); a1.w = fmaf(dw, w1.y, a1.w);
            a2.x = fmaf(dx, w1.z, a2.x); a2.y = fmaf(dy, w1.z, a2.y);
            a2.z = fmaf(dz, w1.z, a2.z); a2.w = fmaf(dw, w1.z, a2.w);
        }
        if (i < cnt) {
            int src0 = packA[base + i];
            float4 w0 = egwp[base + i];
            float4 fs0 = *(const float4*)(fT + (bbase + src0) * C + cg4);
            float dx = fs0.x - ftgt.x, dy = fs0.y - ftgt.y,
                  dz = fs0.z - ftgt.z, dw = fs0.w - ftgt.w;
            a0.x = fmaf(dx, w0.x, a0.x); a0.y = fmaf(dy, w0.x, a0.y);
            a0.z = fmaf(dz, w0.x, a0.z); a0.w = fmaf(dw, w0.x, a0.w);
            a1.x = fmaf(dx, w0.y, a1.x); a1.y = fmaf(dy, w0.y, a1.y);
            a1.z = fmaf(dz, w0.y, a1.z); a1.w = fmaf(dw, w0.y, a1.w);
            a2.x = fmaf(dx, w0.z, a2.x); a2.y = fmaf(dy, w0.z, a2.y);
            a2.z = fmaf(dz, w0.z, a2.z); a2.w = fmaf(dw, w0.z, a2.w);
        }
        // g[k], k = c*3+d, c = 4cg+u  ->  k = 12cg+3u+d: 12 contiguous floats
        float* gp = &g_s[j][cg * 12];
        *(float4*)(gp + 0) = make_float4(a0.x, a1.x, a2.x, a0.y);
        *(float4*)(gp + 4) = make_float4(a1.y, a2.y, a0.z, a1.z);
        *(float4*)(gp + 8) = make_float4(a2.z, a0.w, a1.w, a2.w);
    }
    __syncthreads();

    int m = tid;
    float acc[NPB];
    float bb = b1[m];
    #pragma unroll
    for (int j = 0; j < NPB; ++j) acc[j] = bb;
    for (int k4 = 0; k4 < K1 / 4; ++k4) {
        float4 w = *(const float4*)(W1c + k4 * (MID * 4) + m * 4);
        #pragma unroll
        for (int j = 0; j < NPB; ++j) {
            float4 g = *(const float4*)(&g_s[j][k4 * 4]);  // LDS broadcast
            acc[j] = fmaf(w.x, g.x, fmaf(w.y, g.y, fmaf(w.z, g.z, fmaf(w.w, g.w, acc[j]))));
        }
    }
    #pragma unroll
    for (int j = 0; j < NPB; ++j) {
        float x = acc[j];
        acc[j] = 0.5f * x * (1.0f + erff(x * 0.70710678118654752f));
    }
    __syncthreads();  // all layer-1 reads of g_s complete
    float (*h_s)[MID] = (float (*)[MID])g_s;  // reuse LDS for h
    #pragma unroll
    for (int j = 0; j < NPB; ++j) h_s[j][m] = acc[j];
    __syncthreads();

    float acc2[NPB];
    float bb2 = b2[m];
    #pragma unroll
    for (int j = 0; j < NPB; ++j) acc2[j] = bb2;
    for (int k4 = 0; k4 < MID / 4; ++k4) {
        float4 w = *(const float4*)(W2c + k4 * (OUT * 4) + m * 4);
        #pragma unroll
        for (int j = 0; j < NPB; ++j) {
            float4 h4 = *(const float4*)(&h_s[j][k4 * 4]);
            acc2[j] = fmaf(w.x, h4.x, fmaf(w.y, h4.y, fmaf(w.z, h4.z, fmaf(w.w, h4.w, acc2[j]))));
        }
    }
    #pragma unroll
    for (int j = 0; j < NPB; ++j) fo[((size_t)n0 + j) * OUT + m] = acc2[j];
}

// ---------------- edge aggregation via CSR gather + normalize ----------------
__global__ __launch_bounds__(256) void k_agg(const float* __restrict__ fo,
                                             const float* __restrict__ nw,
                                             const int* __restrict__ rowptr,
                                             const int* __restrict__ packA,
                                             const float* __restrict__ karr,
                                             float* __restrict__ tmp) {
    int tid = threadIdx.x;
    int cg4 = (tid & 31) * 4;
    int s = tid >> 5;              // 0..7
    int n = blockIdx.x * 8 + s;    // flat node over B*N
    size_t bbase = (size_t)(n >> 14) * N;
    int base = rowptr[n], cnt = rowptr[n + 1] - base;
    float4 o = make_float4(0.f, 0.f, 0.f, 0.f);
    float den = 0.f;
    int i = 0;
    for (; i + 2 <= cnt; i += 2) {
        float k0 = karr[base + i], k1 = karr[base + i + 1];
        int src0 = packA[base + i], src1 = packA[base + i + 1];
        float4 f0 = *(const float4*)(fo + (bbase + src0) * OUT + cg4);
        float4 f1 = *(const float4*)(fo + (bbase + src1) * OUT + cg4);
        o.x = fmaf(f0.x, k0, o.x); o.y = fmaf(f0.y, k0, o.y);
        o.z = fmaf(f0.z, k0, o.z); o.w = fmaf(f0.w, k0, o.w);
        o.x = fmaf(f1.x, k1, o.x); o.y = fmaf(f1.y, k1, o.y);
        o.z = fmaf(f1.z, k1, o.z); o.w = fmaf(f1.w, k1, o.w);
        den += k0 + k1;
    }
    if (i < cnt) {
        float k0 = karr[base + i];
        int src0 = packA[base + i];
        float4 f0 = *(const float4*)(fo + (bbase + src0) * OUT + cg4);
        o.x = fmaf(f0.x, k0, o.x); o.y = fmaf(f0.y, k0, o.y);
        o.z = fmaf(f0.z, k0, o.z); o.w = fmaf(f0.w, k0, o.w);
        den += k0;
    }
    float wn = nw[n];  // self edge: d=0 -> kern = nw[n]
    float4 fn = *(const float4*)(fo + (size_t)n * OUT + cg4);
    float inv = 1.f / (den + wn);
    float4 r;
    r.x = (o.x + fn.x * wn) * inv;
    r.y = (o.y + fn.y * wn) * inv;
    r.z = (o.z + fn.z * wn) * inv;
    r.w = (o.w + fn.w * wn) * inv;
    *(float4*)(tmp + (size_t)n * OUT + cg4) = r;
}

// ---------------- output transpose (B,N,OUT) -> (B,OUT,N) ----------------
__global__ __launch_bounds__(256) void k_out_t(const float* __restrict__ tmp,
                                               float* __restrict__ out) {
    __shared__ float t[OUT][65];
    int b = blockIdx.y;
    int n0 = blockIdx.x * 64;
    int tid = threadIdx.x;  // 256
    #pragma unroll
    for (int i = 0; i < 32; ++i) {
        int idx = tid + i * 256;           // 0..8191
        int nl = idx >> 7, o = idx & 127;  // o fastest -> coalesced reads
        t[o][nl] = tmp[(((size_t)b * N + n0 + nl)) * OUT + o];
    }
    __syncthreads();
    #pragma unroll
    for (int i = 0; i < 32; ++i) {
        int idx = tid + i * 256;
        int o = idx >> 6, nl = idx & 63;   // nl fastest -> coalesced writes
        out[((size_t)b * OUT + o) * N + n0 + nl] = t[o][nl];
    }
}

extern "C" void kernel_launch(void* const* d_in, const int* in_sizes, int n_in,
                              void* d_out, int out_size, void* d_ws, size_t ws_size,
                              hipStream_t stream) {
    const float* f     = (const float*)d_in[0];
    const float* nodes = (const float*)d_in[1];
    const float* nw    = (const float*)d_in[2];
    const int*   ei    = (const int*)d_in[3];
    const float* egw   = (const float*)d_in[4];
    const float* W1    = (const float*)d_in[5];
    const float* b1    = (const float*)d_in[6];
    const float* W2    = (const float*)d_in[7];
    const float* b2    = (const float*)d_in[8];
    const float* L     = (const float*)d_in[9];
    const float* cb    = (const float*)d_in[10];
    float* out = (float*)d_out;

    char* ws = (char*)d_ws;
    auto alloc = [&](size_t bytes) {
        void* p = ws;
        ws += (bytes + 255) & ~(size_t)255;
        return p;
    };
    float*  fT     = (float*)alloc((size_t)B * N * C * 4);
    float*  fo     = (float*)alloc((size_t)B * N * OUT * 4);
    float*  tmp    = (float*)alloc((size_t)B * N * OUT * 4);
    float*  W1c    = (float*)alloc((size_t)MID * K1 * 4);
    float*  W2c    = (float*)alloc((size_t)OUT * MID * 4);
    float*  Sig    = (float*)alloc(16 * 4);
    int*    deg    = (int*)alloc((size_t)B * N * 4);
    int*    cursor = (int*)alloc((size_t)B * N * 4);
    int*    rowptr = (int*)alloc(((size_t)B * N + 1) * 4);
    int*    packA  = (int*)alloc((size_t)B * E * 4);
    float4* egwp   = (float4*)alloc((size_t)B * E * 16);
    float*  karr   = (float*)alloc((size_t)B * E * 4);

    hipMemsetAsync(deg, 0, (size_t)B * N * 4, stream);
    hipMemsetAsync(cursor, 0, (size_t)B * N * 4, stream);

    k_prep<<<1, 128, 0, stream>>>(W1, W2, L, W1c, W2c, Sig);
    k_transpose<<<dim3(N / 32, C / 32, B), dim3(32, 8), 0, stream>>>(f, fT);
    k_count<<<(B * E) / 256, 256, 0, stream>>>(ei, deg);
    k_scan<<<1, 1024, 0, stream>>>(deg, rowptr);
    k_fill<<<(B * E) / 256, 256, 0, stream>>>(ei, egw, nodes, nw, Sig, cb, rowptr,
                                              cursor, packA, egwp, karr);
    k_grad_mlp<<<(B * N) / NPB, 128, 0, stream>>>(fT, rowptr, packA, egwp, W1c, b1,
                                                  W2c, b2, fo);
    k_agg<<<(B * N) / 8, 256, 0, stream>>>(fo, nw, rowptr, packA, karr, tmp);
    k_out_t<<<dim3(N / 64, B), 256, 0, stream>>>(tmp, out);
}

// Round 4
// 273.550 us; speedup vs baseline: 9.0298x; 1.4192x over previous
//
#include <hip/hip_runtime.h>
#include <hip/hip_bf16.h>

// Problem constants
static constexpr int B   = 4;
static constexpr int N   = 16384;   // 2^14
static constexpr int E   = 131072;  // 2^17
static constexpr int C   = 128;
static constexpr int ND  = 3;
static constexpr int MID = 128;
static constexpr int OUT = 128;
static constexpr int K1  = C * ND;  // 384
static constexpr int NT  = 64;      // nodes per block in fused grad+MLP
static constexpr int K1P = 392;     // padded LDS row (+8 bf16 = 2-way max conflict)

typedef __attribute__((ext_vector_type(8))) short bf16x8;
typedef __attribute__((ext_vector_type(4))) float f32x4;

__device__ __forceinline__ ushort f2bf(float x) {
    union { float f; unsigned u; } v; v.f = x;
    return (ushort)((v.u + 0x7fffu + ((v.u >> 16) & 1u)) >> 16);  // RNE
}
__device__ __forceinline__ float bf2f(ushort u) {
    union { unsigned u; float f; } v; v.u = (unsigned)u << 16;
    return v.f;
}

// ---------------- prep: W1/W2 -> bf16 MFMA B-fragment order; Sigma = L L^T ----
// B-frag for 16x16x32: lane l holds B[k][n], n = nt*16+(l&15), k = t*32+(l>>4)*8+j
__global__ void k_prep(const float* __restrict__ W1, const float* __restrict__ W2,
                       const float* __restrict__ L, ushort* __restrict__ W1p,
                       ushort* __restrict__ W2p, float* __restrict__ Sig) {
    int tid = threadIdx.x;  // 256
    for (int i = tid; i < 8 * 12 * 64 * 8; i += 256) {
        int j = i & 7, l = (i >> 3) & 63, t = (i >> 9) % 12, nt = (i >> 9) / 12;
        int n = nt * 16 + (l & 15);
        int k = t * 32 + ((l >> 4) & 3) * 8 + j;
        W1p[i] = f2bf(W1[n * K1 + k]);
    }
    for (int i = tid; i < 8 * 4 * 64 * 8; i += 256) {
        int j = i & 7, l = (i >> 3) & 63, t = (i >> 9) % 4, nt = (i >> 9) / 4;
        int n = nt * 16 + (l & 15);
        int k = t * 32 + ((l >> 4) & 3) * 8 + j;
        W2p[i] = f2bf(W2[n * MID + k]);
    }
    if (tid < 9) {
        int i = tid / 3, j = tid % 3;
        Sig[tid] = L[i * 3 + 0] * L[j * 3 + 0] + L[i * 3 + 1] * L[j * 3 + 1] +
                   L[i * 3 + 2] * L[j * 3 + 2];
    }
}

// ---------------- transpose f (B,C,N) f32 -> fT (B,N,C) bf16 ----------------
__global__ void k_transpose(const float* __restrict__ f, ushort* __restrict__ fT) {
    __shared__ float tile[32][33];
    int b = blockIdx.z;
    int n0 = blockIdx.x * 32, c0 = blockIdx.y * 32;
    const float* fb = f + (size_t)b * C * N;
    ushort* fTb = fT + (size_t)b * N * C;
    int tx = threadIdx.x, ty = threadIdx.y;  // (32,8)
    #pragma unroll
    for (int i = 0; i < 32; i += 8)
        tile[ty + i][tx] = fb[(size_t)(c0 + ty + i) * N + n0 + tx];
    __syncthreads();
    #pragma unroll
    for (int i = 0; i < 32; i += 8)
        fTb[(size_t)(n0 + ty + i) * C + c0 + tx] = f2bf(tile[tx][ty + i]);
}

// ---------------- CSR build: count degrees by target ----------------
__global__ void k_count(const int* __restrict__ ei, int* __restrict__ deg) {
    int idx = blockIdx.x * 256 + threadIdx.x;  // 0..B*E-1
    if (idx >= B * E) return;
    int b = idx >> 17;
    int tgt = ei[(size_t)idx * 2 + 1];
    atomicAdd(&deg[b * N + tgt], 1);
}

// ---------------- exclusive scan over B*N = 65536 counters (single block) ----
__global__ __launch_bounds__(1024) void k_scan(const int4* __restrict__ degv,
                                               int* __restrict__ rowptr) {
    __shared__ int s[1024];
    int tv = threadIdx.x;
    int4 loc[16];
    int sum = 0;
    #pragma unroll
    for (int i = 0; i < 16; ++i) {
        loc[i] = degv[tv * 16 + i];
        sum += loc[i].x + loc[i].y + loc[i].z + loc[i].w;
    }
    s[tv] = sum;
    __syncthreads();
    for (int d = 1; d < 1024; d <<= 1) {
        int v = s[tv];
        int u = (tv >= d) ? s[tv - d] : 0;
        __syncthreads();
        s[tv] = v + u;
        __syncthreads();
    }
    int run = (tv == 0) ? 0 : s[tv - 1];
    int4* rp = (int4*)(rowptr + tv * 64);
    #pragma unroll
    for (int i = 0; i < 16; ++i) {
        int4 d = loc[i];
        int4 w;
        w.x = run;
        w.y = run + d.x;
        w.z = w.y + d.y;
        w.w = w.z + d.z;
        run = w.w + d.w;
        rp[i] = w;
    }
    if (tv == 1023) rowptr[B * N] = run;
}

// ---------------- CSR fill: edge weights + src (packed), Gaussian kernel + src ----
__global__ void k_fill(const int* __restrict__ ei, const float* __restrict__ egw,
                       const float* __restrict__ nodes, const float* __restrict__ nw,
                       const float* __restrict__ Sig, const float* __restrict__ cb,
                       const int* __restrict__ rowptr, int* __restrict__ cursor,
                       float4* __restrict__ egwp, float2* __restrict__ ka2) {
    int idx = blockIdx.x * 256 + threadIdx.x;  // 0..B*E-1
    if (idx >= B * E) return;
    int b = idx >> 17;
    int src = ei[(size_t)idx * 2], tgt = ei[(size_t)idx * 2 + 1];
    int bn = b * N + tgt;
    int pos = atomicAdd(&cursor[bn], 1);
    int o = rowptr[bn] + pos;
    const float* w = egw + (size_t)idx * ND;
    egwp[o] = make_float4(w[0], w[1], w[2], __int_as_float(src));
    const float* ns = nodes + ((size_t)b * N + src) * ND;
    const float* nt = nodes + (size_t)bn * ND;
    float d0 = ns[0] - nt[0], d1 = ns[1] - nt[1], d2 = ns[2] - nt[2];
    float q = d0 * (Sig[0] * d0 + Sig[1] * d1 + Sig[2] * d2) +
              d1 * (Sig[3] * d0 + Sig[4] * d1 + Sig[5] * d2) +
              d2 * (Sig[6] * d0 + Sig[7] * d1 + Sig[8] * d2) +
              d0 * cb[0] + d1 * cb[1] + d2 * cb[2];
    ka2[o] = make_float2(nw[(size_t)b * N + src] * expf(-q), __int_as_float(src));
}

// ---------------- fused gradient gather (VALU) + pointwise MLP (MFMA) --------
// Phase 1: 8 slots x 32 lanes gather g for 64 nodes -> LDS bf16 [64][392].
// Phase 2: wave w owns 16-node mtile; A-frags (12) cached in regs; W1/W2
// B-frags streamed from global (prepacked); h staged in LDS (aliases g_s).
__global__ __launch_bounds__(256, 3) void k_grad_mlp(
    const ushort* __restrict__ fT, const int* __restrict__ rowptr,
    const float4* __restrict__ egwp, const ushort* __restrict__ W1p,
    const float* __restrict__ b1, const ushort* __restrict__ W2p,
    const float* __restrict__ b2, ushort* __restrict__ fo) {
    __shared__ ushort g_s[NT][K1P];  // 50176 B
    int tid = threadIdx.x;
    int n0 = blockIdx.x * NT;  // flat node over B*N

    {  // ---- gather phase ----
        int cg = tid & 31, s = tid >> 5;  // 32 channel-groups x 8 node slots
        int cg4 = cg * 4;
        for (int jj = 0; jj < NT; jj += 8) {
            int j = jj + s;
            int n = n0 + j;
            const ushort* fTb = fT + (size_t)(n >> 14) * N * C;  // batch base
            float4 ft;
            {
                ushort4 u = *(const ushort4*)(fT + (size_t)n * C + cg4);
                ft = make_float4(bf2f(u.x), bf2f(u.y), bf2f(u.z), bf2f(u.w));
            }
            int base = rowptr[n], cnt = rowptr[n + 1] - base;
            float4 a0 = make_float4(0.f, 0.f, 0.f, 0.f), a1 = a0, a2 = a0;
            int i = 0;
            for (; i + 2 <= cnt; i += 2) {
                float4 w0 = egwp[base + i];
                float4 w1 = egwp[base + i + 1];
                int src0 = __float_as_int(w0.w);
                int src1 = __float_as_int(w1.w);
                ushort4 u0 = *(const ushort4*)(fTb + (size_t)src0 * C + cg4);
                ushort4 u1 = *(const ushort4*)(fTb + (size_t)src1 * C + cg4);
                float dx = bf2f(u0.x) - ft.x, dy = bf2f(u0.y) - ft.y,
                      dz = bf2f(u0.z) - ft.z, dw = bf2f(u0.w) - ft.w;
                a0.x = fmaf(dx, w0.x, a0.x); a0.y = fmaf(dy, w0.x, a0.y);
                a0.z = fmaf(dz, w0.x, a0.z); a0.w = fmaf(dw, w0.x, a0.w);
                a1.x = fmaf(dx, w0.y, a1.x); a1.y = fmaf(dy, w0.y, a1.y);
                a1.z = fmaf(dz, w0.y, a1.z); a1.w = fmaf(dw, w0.y, a1.w);
                a2.x = fmaf(dx, w0.z, a2.x); a2.y = fmaf(dy, w0.z, a2.y);
                a2.z = fmaf(dz, w0.z, a2.z); a2.w = fmaf(dw, w0.z, a2.w);
                dx = bf2f(u1.x) - ft.x; dy = bf2f(u1.y) - ft.y;
                dz = bf2f(u1.z) - ft.z; dw = bf2f(u1.w) - ft.w;
                a0.x = fmaf(dx, w1.x, a0.x); a0.y = fmaf(dy, w1.x, a0.y);
                a0.z = fmaf(dz, w1.x, a0.z); a0.w = fmaf(dw, w1.x, a0.w);
                a1.x = fmaf(dx, w1.y, a1.x); a1.y = fmaf(dy, w1.y, a1.y);
                a1.z = fmaf(dz, w1.y, a1.z); a1.w = fmaf(dw, w1.y, a1.w);
                a2.x = fmaf(dx, w1.z, a2.x); a2.y = fmaf(dy, w1.z, a2.y);
                a2.z = fmaf(dz, w1.z, a2.z); a2.w = fmaf(dw, w1.z, a2.w);
            }
            if (i < cnt) {
                float4 w0 = egwp[base + i];
                int src0 = __float_as_int(w0.w);
                ushort4 u0 = *(const ushort4*)(fTb + (size_t)src0 * C + cg4);
                float dx = bf2f(u0.x) - ft.x, dy = bf2f(u0.y) - ft.y,
                      dz = bf2f(u0.z) - ft.z, dw = bf2f(u0.w) - ft.w;
                a0.x = fmaf(dx, w0.x, a0.x); a0.y = fmaf(dy, w0.x, a0.y);
                a0.z = fmaf(dz, w0.x, a0.z); a0.w = fmaf(dw, w0.x, a0.w);
                a1.x = fmaf(dx, w0.y, a1.x); a1.y = fmaf(dy, w0.y, a1.y);
                a1.z = fmaf(dz, w0.y, a1.z); a1.w = fmaf(dw, w0.y, a1.w);
                a2.x = fmaf(dx, w0.z, a2.x); a2.y = fmaf(dy, w0.z, a2.y);
                a2.z = fmaf(dz, w0.z, a2.z); a2.w = fmaf(dw, w0.z, a2.w);
            }
            // g[k], k = c*3+d, c = 4cg+u -> k = 12cg+3u+d: 12 contiguous bf16
            unsigned p0 = (unsigned)f2bf(a0.x) | ((unsigned)f2bf(a1.x) << 16);
            unsigned p1 = (unsigned)f2bf(a2.x) | ((unsigned)f2bf(a0.y) << 16);
            unsigned p2 = (unsigned)f2bf(a1.y) | ((unsigned)f2bf(a2.y) << 16);
            unsigned p3 = (unsigned)f2bf(a0.z) | ((unsigned)f2bf(a1.z) << 16);
            unsigned p4 = (unsigned)f2bf(a2.z) | ((unsigned)f2bf(a0.w) << 16);
            unsigned p5 = (unsigned)f2bf(a1.w) | ((unsigned)f2bf(a2.w) << 16);
            uint2* dst = (uint2*)&g_s[j][cg * 12];
            dst[0] = make_uint2(p0, p1);
            dst[1] = make_uint2(p2, p3);
            dst[2] = make_uint2(p4, p5);
        }
    }
    __syncthreads();

    // ---- MFMA phase ----
    int wv = tid >> 6, ln = tid & 63, lr = ln & 15, lh = ln >> 4;
    bf16x8 a[12];  // A-frags for this wave's 16-node mtile, all K
    {
        const ushort* grow = &g_s[wv * 16 + lr][0];
        #pragma unroll
        for (int t = 0; t < 12; ++t)
            a[t] = *(const bf16x8*)(grow + t * 32 + lh * 8);
    }
    __syncthreads();  // all A-reads done before h_s (aliasing g_s) is written

    ushort(*h_s)[136] = (ushort(*)[136]) & g_s[0][0];  // 17408 B alias
    const bf16x8* W1f = (const bf16x8*)W1p;
    for (int nt = 0; nt < 8; ++nt) {
        float bb = b1[nt * 16 + lr];
        f32x4 c = {bb, bb, bb, bb};
        #pragma unroll
        for (int t = 0; t < 12; ++t)
            c = __builtin_amdgcn_mfma_f32_16x16x32_bf16(
                a[t], W1f[(nt * 12 + t) * 64 + ln], c, 0, 0, 0);
        #pragma unroll
        for (int r = 0; r < 4; ++r) {
            float x = c[r];
            x = 0.5f * x * (1.0f + erff(x * 0.70710678118654752f));
            h_s[wv * 16 + lh * 4 + r][nt * 16 + lr] = f2bf(x);  // D: row=lh*4+r, col=lr
        }
    }
    __syncthreads();  // (wave-local rows, but barrier is cheap + safe)

    bf16x8 a2[4];
    {
        const ushort* hrow = &h_s[wv * 16 + lr][0];
        #pragma unroll
        for (int t = 0; t < 4; ++t)
            a2[t] = *(const bf16x8*)(hrow + t * 32 + lh * 8);
    }
    const bf16x8* W2f = (const bf16x8*)W2p;
    for (int nt = 0; nt < 8; ++nt) {
        float bb = b2[nt * 16 + lr];
        f32x4 c = {bb, bb, bb, bb};
        #pragma unroll
        for (int t = 0; t < 4; ++t)
            c = __builtin_amdgcn_mfma_f32_16x16x32_bf16(
                a2[t], W2f[(nt * 4 + t) * 64 + ln], c, 0, 0, 0);
        #pragma unroll
        for (int r = 0; r < 4; ++r)
            fo[(size_t)(n0 + wv * 16 + lh * 4 + r) * OUT + nt * 16 + lr] = f2bf(c[r]);
    }
}

// ---------------- edge aggregation (CSR gather) + normalize + fused transpose ----
__global__ __launch_bounds__(256) void k_agg_t(const ushort* __restrict__ fo,
                                               const float* __restrict__ nw,
                                               const int* __restrict__ rowptr,
                                               const float2* __restrict__ ka2,
                                               float* __restrict__ out) {
    __shared__ float t[OUT][65];
    int tid = threadIdx.x;
    int cg4 = (tid & 31) * 4;
    int s = tid >> 5;                // 0..7
    int n0 = blockIdx.x * 64;        // flat node over B*N
    int b = n0 >> 14, ncol0 = n0 & (N - 1);
    const ushort* fob = fo + (size_t)b * N * OUT;
    for (int g = 0; g < 8; ++g) {
        int nl = g * 8 + s;
        int n = n0 + nl;
        int base = rowptr[n], cnt = rowptr[n + 1] - base;
        float4 o = make_float4(0.f, 0.f, 0.f, 0.f);
        float den = 0.f;
        int i = 0;
        for (; i + 2 <= cnt; i += 2) {
            float2 k0 = ka2[base + i];
            float2 k1 = ka2[base + i + 1];
            int src0 = __float_as_int(k0.y);
            int src1 = __float_as_int(k1.y);
            ushort4 u0 = *(const ushort4*)(fob + (size_t)src0 * OUT + cg4);
            ushort4 u1 = *(const ushort4*)(fob + (size_t)src1 * OUT + cg4);
            o.x = fmaf(bf2f(u0.x), k0.x, o.x); o.y = fmaf(bf2f(u0.y), k0.x, o.y);
            o.z = fmaf(bf2f(u0.z), k0.x, o.z); o.w = fmaf(bf2f(u0.w), k0.x, o.w);
            o.x = fmaf(bf2f(u1.x), k1.x, o.x); o.y = fmaf(bf2f(u1.y), k1.x, o.y);
            o.z = fmaf(bf2f(u1.z), k1.x, o.z); o.w = fmaf(bf2f(u1.w), k1.x, o.w);
            den += k0.x + k1.x;
        }
        if (i < cnt) {
            float2 k0 = ka2[base + i];
            int src0 = __float_as_int(k0.y);
            ushort4 u0 = *(const ushort4*)(fob + (size_t)src0 * OUT + cg4);
            o.x = fmaf(bf2f(u0.x), k0.x, o.x); o.y = fmaf(bf2f(u0.y), k0.x, o.y);
            o.z = fmaf(bf2f(u0.z), k0.x, o.z); o.w = fmaf(bf2f(u0.w), k0.x, o.w);
            den += k0.x;
        }
        float wn = nw[n];  // self edge: d=0 -> kern = nw[n]
        ushort4 uf = *(const ushort4*)(fo + (size_t)n * OUT + cg4);
        float inv = 1.f / (den + wn);
        t[cg4 + 0][nl] = (o.x + bf2f(uf.x) * wn) * inv;
        t[cg4 + 1][nl] = (o.y + bf2f(uf.y) * wn) * inv;
        t[cg4 + 2][nl] = (o.z + bf2f(uf.z) * wn) * inv;
        t[cg4 + 3][nl] = (o.w + bf2f(uf.w) * wn) * inv;
    }
    __syncthreads();
    #pragma unroll
    for (int i = 0; i < 32; ++i) {
        int idx = tid + i * 256;
        int o = idx >> 6, nl = idx & 63;  // nl fastest -> coalesced writes
        out[((size_t)b * OUT + o) * N + ncol0 + nl] = t[o][nl];
    }
}

extern "C" void kernel_launch(void* const* d_in, const int* in_sizes, int n_in,
                              void* d_out, int out_size, void* d_ws, size_t ws_size,
                              hipStream_t stream) {
    const float* f     = (const float*)d_in[0];
    const float* nodes = (const float*)d_in[1];
    const float* nw    = (const float*)d_in[2];
    const int*   ei    = (const int*)d_in[3];
    const float* egw   = (const float*)d_in[4];
    const float* W1    = (const float*)d_in[5];
    const float* b1    = (const float*)d_in[6];
    const float* W2    = (const float*)d_in[7];
    const float* b2    = (const float*)d_in[8];
    const float* L     = (const float*)d_in[9];
    const float* cb    = (const float*)d_in[10];
    float* out = (float*)d_out;

    char* ws = (char*)d_ws;
    auto alloc = [&](size_t bytes) {
        void* p = ws;
        ws += (bytes + 255) & ~(size_t)255;
        return p;
    };
    ushort* fT     = (ushort*)alloc((size_t)B * N * C * 2);
    ushort* fo     = (ushort*)alloc((size_t)B * N * OUT * 2);
    ushort* W1p    = (ushort*)alloc((size_t)MID * K1 * 2);
    ushort* W2p    = (ushort*)alloc((size_t)OUT * MID * 2);
    float*  Sig    = (float*)alloc(16 * 4);
    int*    deg    = (int*)alloc((size_t)B * N * 4);
    int*    cursor = (int*)alloc((size_t)B * N * 4);
    int*    rowptr = (int*)alloc(((size_t)B * N + 4) * 4);
    float4* egwp   = (float4*)alloc((size_t)B * E * 16);
    float2* ka2    = (float2*)alloc((size_t)B * E * 8);

    hipMemsetAsync(deg, 0, (size_t)B * N * 4, stream);
    hipMemsetAsync(cursor, 0, (size_t)B * N * 4, stream);

    k_prep<<<1, 256, 0, stream>>>(W1, W2, L, W1p, W2p, Sig);
    k_transpose<<<dim3(N / 32, C / 32, B), dim3(32, 8), 0, stream>>>(f, fT);
    k_count<<<(B * E) / 256, 256, 0, stream>>>(ei, deg);
    k_scan<<<1, 1024, 0, stream>>>((const int4*)deg, rowptr);
    k_fill<<<(B * E) / 256, 256, 0, stream>>>(ei, egw, nodes, nw, Sig, cb, rowptr,
                                              cursor, egwp, ka2);
    k_grad_mlp<<<(B * N) / NT, 256, 0, stream>>>(fT, rowptr, egwp, W1p, b1, W2p,
                                                 b2, fo);
    k_agg_t<<<(B * N) / 64, 256, 0, stream>>>(fo, nw, rowptr, ka2, out);
}

// Round 5
// 226.143 us; speedup vs baseline: 10.9227x; 1.2096x over previous
//
#include <hip/hip_runtime.h>
#include <hip/hip_bf16.h>

// Problem constants
static constexpr int B   = 4;
static constexpr int N   = 16384;   // 2^14
static constexpr int E   = 131072;  // 2^17
static constexpr int C   = 128;
static constexpr int ND  = 3;
static constexpr int MID = 128;
static constexpr int OUT = 128;
static constexpr int K1  = C * ND;  // 384
static constexpr int NT  = 64;      // nodes per block in fused grad+MLP
static constexpr int K1P = 392;     // padded LDS row (2-way max bank conflict)

typedef __attribute__((ext_vector_type(8))) short bf16x8;
typedef __attribute__((ext_vector_type(4))) float f32x4;

__device__ __forceinline__ ushort f2bf(float x) {
    union { float f; unsigned u; } v; v.f = x;
    return (ushort)((v.u + 0x7fffu + ((v.u >> 16) & 1u)) >> 16);  // RNE
}
__device__ __forceinline__ float bf2f(ushort u) {
    union { unsigned u; float f; } v; v.u = (unsigned)u << 16;
    return v.f;
}

// ---------------- prep: W1/W2 -> bf16 MFMA B-fragment order; Sigma = L L^T ----
// B-frag for 16x16x32: lane l holds B[k][n], n = nt*16+(l&15), k = t*32+(l>>4)*8+j
__global__ void k_prep(const float* __restrict__ W1, const float* __restrict__ W2,
                       const float* __restrict__ L, ushort* __restrict__ W1p,
                       ushort* __restrict__ W2p, float* __restrict__ Sig) {
    int tid = threadIdx.x;  // 256
    for (int i = tid; i < 8 * 12 * 64 * 8; i += 256) {
        int j = i & 7, l = (i >> 3) & 63, t = (i >> 9) % 12, nt = (i >> 9) / 12;
        int n = nt * 16 + (l & 15);
        int k = t * 32 + ((l >> 4) & 3) * 8 + j;
        W1p[i] = f2bf(W1[n * K1 + k]);
    }
    for (int i = tid; i < 8 * 4 * 64 * 8; i += 256) {
        int j = i & 7, l = (i >> 3) & 63, t = (i >> 9) % 4, nt = (i >> 9) / 4;
        int n = nt * 16 + (l & 15);
        int k = t * 32 + ((l >> 4) & 3) * 8 + j;
        W2p[i] = f2bf(W2[n * MID + k]);
    }
    if (tid < 9) {
        int i = tid / 3, j = tid % 3;
        Sig[tid] = L[i * 3 + 0] * L[j * 3 + 0] + L[i * 3 + 1] * L[j * 3 + 1] +
                   L[i * 3 + 2] * L[j * 3 + 2];
    }
}

// ---------------- transpose f (B,C,N) f32 -> fT (B,N,C) bf16 ----------------
__global__ void k_transpose(const float* __restrict__ f, ushort* __restrict__ fT) {
    __shared__ float tile[32][33];
    int b = blockIdx.z;
    int n0 = blockIdx.x * 32, c0 = blockIdx.y * 32;
    const float* fb = f + (size_t)b * C * N;
    ushort* fTb = fT + (size_t)b * N * C;
    int tx = threadIdx.x, ty = threadIdx.y;  // (32,8)
    #pragma unroll
    for (int i = 0; i < 32; i += 8)
        tile[ty + i][tx] = fb[(size_t)(c0 + ty + i) * N + n0 + tx];
    __syncthreads();
    #pragma unroll
    for (int i = 0; i < 32; i += 8)
        fTb[(size_t)(n0 + ty + i) * C + c0 + tx] = f2bf(tile[tx][ty + i]);
}

// ---------------- CSR build: count degrees by target ----------------
__global__ void k_count(const int2* __restrict__ ei2, int* __restrict__ deg) {
    int idx = blockIdx.x * 256 + threadIdx.x;  // 0..B*E-1
    int b = idx >> 17;
    int tgt = ei2[idx].y;
    atomicAdd(&deg[b * N + tgt], 1);
}

// ---------------- hierarchical exclusive scan over 65536 ints ----------------
__global__ void k_scan1(const int4* __restrict__ degv, int* __restrict__ rowptr,
                        int* __restrict__ bsum) {
    __shared__ int s[256];
    int blk = blockIdx.x, t = threadIdx.x;
    int4 d = degv[blk * 256 + t];
    s[t] = d.x + d.y + d.z + d.w;
    __syncthreads();
    for (int off = 1; off < 256; off <<= 1) {
        int v = s[t];
        int u = (t >= off) ? s[t - off] : 0;
        __syncthreads();
        s[t] = v + u;
        __syncthreads();
    }
    int excl = (t == 0) ? 0 : s[t - 1];
    if (t == 255) bsum[blk] = s[255];
    int4 w;
    w.x = excl;
    w.y = excl + d.x;
    w.z = w.y + d.y;
    w.w = w.z + d.z;
    ((int4*)rowptr)[blk * 256 + t] = w;
}

__global__ void k_scan2(int* __restrict__ bsum, int* __restrict__ rowptr) {
    __shared__ int s[64];
    int t = threadIdx.x;  // 64
    s[t] = bsum[t];
    __syncthreads();
    for (int off = 1; off < 64; off <<= 1) {
        int v = s[t];
        int u = (t >= off) ? s[t - off] : 0;
        __syncthreads();
        s[t] = v + u;
        __syncthreads();
    }
    bsum[t] = (t == 0) ? 0 : s[t - 1];
    if (t == 63) rowptr[B * N] = s[63];
}

__global__ void k_scan3(int4* __restrict__ rowv, const int* __restrict__ bsum) {
    int i = blockIdx.x * 256 + threadIdx.x;  // 0..16383 (int4 index)
    int add = bsum[i >> 8];                  // 256 int4 per scan1 block
    int4 v = rowv[i];
    v.x += add; v.y += add; v.z += add; v.w += add;
    rowv[i] = v;
}

// ---------------- CSR fill pass 1: scatter edge id (4B) ----------------
__global__ void k_fill_perm(const int2* __restrict__ ei2,
                            const int* __restrict__ rowptr,
                            int* __restrict__ cursor, int* __restrict__ perm) {
    int idx = blockIdx.x * 256 + threadIdx.x;
    int b = idx >> 17;
    int tgt = ei2[idx].y;
    int bn = b * N + tgt;
    int pos = atomicAdd(&cursor[bn], 1);
    perm[rowptr[bn] + pos] = idx;
}

// ---------------- CSR fill pass 2: coalesced expand (egwp, ka2) ----------------
__global__ void k_fill_expand(const int* __restrict__ perm,
                              const int2* __restrict__ ei2,
                              const float* __restrict__ egw,
                              const float* __restrict__ nodes,
                              const float* __restrict__ nw,
                              const float* __restrict__ Sig,
                              const float* __restrict__ cb,
                              float4* __restrict__ egwp, float2* __restrict__ ka2) {
    int o = blockIdx.x * 256 + threadIdx.x;
    int idx = perm[o];
    int b = idx >> 17;
    int2 e = ei2[idx];
    int src = e.x, tgt = e.y;
    const float* w = egw + (size_t)idx * ND;
    egwp[o] = make_float4(w[0], w[1], w[2], __int_as_float(src));
    const float* ns = nodes + ((size_t)b * N + src) * ND;
    const float* nt = nodes + ((size_t)b * N + tgt) * ND;
    float d0 = ns[0] - nt[0], d1 = ns[1] - nt[1], d2 = ns[2] - nt[2];
    float q = d0 * (Sig[0] * d0 + Sig[1] * d1 + Sig[2] * d2) +
              d1 * (Sig[3] * d0 + Sig[4] * d1 + Sig[5] * d2) +
              d2 * (Sig[6] * d0 + Sig[7] * d1 + Sig[8] * d2) +
              d0 * cb[0] + d1 * cb[1] + d2 * cb[2];
    ka2[o] = make_float2(nw[(size_t)b * N + src] * expf(-q), __int_as_float(src));
}

#define EDGE_FMA(W, U)                                                         \
    {                                                                          \
        float dx = bf2f(U.x) - ft.x, dy = bf2f(U.y) - ft.y,                    \
              dz = bf2f(U.z) - ft.z, dw = bf2f(U.w) - ft.w;                    \
        a0.x = fmaf(dx, W.x, a0.x); a0.y = fmaf(dy, W.x, a0.y);                \
        a0.z = fmaf(dz, W.x, a0.z); a0.w = fmaf(dw, W.x, a0.w);                \
        a1.x = fmaf(dx, W.y, a1.x); a1.y = fmaf(dy, W.y, a1.y);                \
        a1.z = fmaf(dz, W.y, a1.z); a1.w = fmaf(dw, W.y, a1.w);                \
        a2.x = fmaf(dx, W.z, a2.x); a2.y = fmaf(dy, W.z, a2.y);                \
        a2.z = fmaf(dz, W.z, a2.z); a2.w = fmaf(dw, W.z, a2.w);                \
    }

// ---------------- fused gradient gather (VALU) + pointwise MLP (MFMA) --------
// 512 threads: gather = 16 slots x 32 lanes, unroll-4; MFMA = 8 waves,
// wave = (mtile mt = wv&3, nt-half nh = wv>>2). LDS 50KB -> 3 blk/CU = 24 waves.
__global__ __launch_bounds__(512, 5) void k_grad_mlp(
    const ushort* __restrict__ fT, const int* __restrict__ rowptr,
    const float4* __restrict__ egwp, const ushort* __restrict__ W1p,
    const float* __restrict__ b1, const ushort* __restrict__ W2p,
    const float* __restrict__ b2, ushort* __restrict__ fo) {
    __shared__ ushort g_s[NT][K1P];  // 50176 B
    int tid = threadIdx.x;
    int n0 = blockIdx.x * NT;  // flat node over B*N

    {  // ---- gather phase ----
        int cg = tid & 31, s = tid >> 5;  // 32 channel-groups x 16 node slots
        int cg4 = cg * 4;
        for (int jj = 0; jj < NT; jj += 16) {
            int j = jj + s;
            int n = n0 + j;
            const ushort* fTb = fT + (size_t)(n >> 14) * N * C;  // batch base
            float4 ft;
            {
                ushort4 u = *(const ushort4*)(fT + (size_t)n * C + cg4);
                ft = make_float4(bf2f(u.x), bf2f(u.y), bf2f(u.z), bf2f(u.w));
            }
            int base = rowptr[n], cnt = rowptr[n + 1] - base;
            float4 a0 = make_float4(0.f, 0.f, 0.f, 0.f), a1 = a0, a2 = a0;
            int i = 0;
            for (; i + 4 <= cnt; i += 4) {
                float4 w0 = egwp[base + i];
                float4 w1 = egwp[base + i + 1];
                float4 w2 = egwp[base + i + 2];
                float4 w3 = egwp[base + i + 3];
                ushort4 u0 = *(const ushort4*)(fTb + (size_t)__float_as_int(w0.w) * C + cg4);
                ushort4 u1 = *(const ushort4*)(fTb + (size_t)__float_as_int(w1.w) * C + cg4);
                ushort4 u2 = *(const ushort4*)(fTb + (size_t)__float_as_int(w2.w) * C + cg4);
                ushort4 u3 = *(const ushort4*)(fTb + (size_t)__float_as_int(w3.w) * C + cg4);
                EDGE_FMA(w0, u0);
                EDGE_FMA(w1, u1);
                EDGE_FMA(w2, u2);
                EDGE_FMA(w3, u3);
            }
            for (; i < cnt; ++i) {
                float4 w0 = egwp[base + i];
                ushort4 u0 = *(const ushort4*)(fTb + (size_t)__float_as_int(w0.w) * C + cg4);
                EDGE_FMA(w0, u0);
            }
            // g[k], k = c*3+d, c = 4cg+u -> k = 12cg+3u+d: 12 contiguous bf16
            unsigned p0 = (unsigned)f2bf(a0.x) | ((unsigned)f2bf(a1.x) << 16);
            unsigned p1 = (unsigned)f2bf(a2.x) | ((unsigned)f2bf(a0.y) << 16);
            unsigned p2 = (unsigned)f2bf(a1.y) | ((unsigned)f2bf(a2.y) << 16);
            unsigned p3 = (unsigned)f2bf(a0.z) | ((unsigned)f2bf(a1.z) << 16);
            unsigned p4 = (unsigned)f2bf(a2.z) | ((unsigned)f2bf(a0.w) << 16);
            unsigned p5 = (unsigned)f2bf(a1.w) | ((unsigned)f2bf(a2.w) << 16);
            uint2* dst = (uint2*)&g_s[j][cg * 12];
            dst[0] = make_uint2(p0, p1);
            dst[1] = make_uint2(p2, p3);
            dst[2] = make_uint2(p4, p5);
        }
    }
    __syncthreads();

    // ---- MFMA phase: 8 waves = 4 mtiles x 2 nt-halves ----
    int wv = tid >> 6, ln = tid & 63, lr = ln & 15, lh = ln >> 4;
    int mt = wv & 3, nh = wv >> 2;
    bf16x8 a[12];  // A-frags for this wave's 16-node mtile, all K
    {
        const ushort* grow = &g_s[mt * 16 + lr][0];
        #pragma unroll
        for (int t = 0; t < 12; ++t)
            a[t] = *(const bf16x8*)(grow + t * 32 + lh * 8);
    }
    __syncthreads();  // all A-reads done before h_s (aliasing g_s) is written

    ushort(*h_s)[136] = (ushort(*)[136]) & g_s[0][0];  // 17408 B alias
    const bf16x8* W1f = (const bf16x8*)W1p;
    #pragma unroll
    for (int q = 0; q < 4; ++q) {
        int nt = nh * 4 + q;
        float bb = b1[nt * 16 + lr];
        f32x4 c = {bb, bb, bb, bb};
        #pragma unroll
        for (int t = 0; t < 12; ++t)
            c = __builtin_amdgcn_mfma_f32_16x16x32_bf16(
                a[t], W1f[(nt * 12 + t) * 64 + ln], c, 0, 0, 0);
        #pragma unroll
        for (int r = 0; r < 4; ++r) {
            float x = c[r];
            x = 0.5f * x * (1.0f + erff(x * 0.70710678118654752f));
            h_s[mt * 16 + lh * 4 + r][nt * 16 + lr] = f2bf(x);  // row=node, col=mid
        }
    }
    __syncthreads();  // both nt-halves of h complete

    bf16x8 a2[4];
    {
        const ushort* hrow = &h_s[mt * 16 + lr][0];
        #pragma unroll
        for (int t = 0; t < 4; ++t)
            a2[t] = *(const bf16x8*)(hrow + t * 32 + lh * 8);
    }
    const bf16x8* W2f = (const bf16x8*)W2p;
    #pragma unroll
    for (int q = 0; q < 4; ++q) {
        int nt = nh * 4 + q;
        float bb = b2[nt * 16 + lr];
        f32x4 c = {bb, bb, bb, bb};
        #pragma unroll
        for (int t = 0; t < 4; ++t)
            c = __builtin_amdgcn_mfma_f32_16x16x32_bf16(
                a2[t], W2f[(nt * 4 + t) * 64 + ln], c, 0, 0, 0);
        #pragma unroll
        for (int r = 0; r < 4; ++r)
            fo[(size_t)(n0 + mt * 16 + lh * 4 + r) * OUT + nt * 16 + lr] = f2bf(c[r]);
    }
}

#define AGG_FMA(K, U)                                                          \
    {                                                                          \
        o.x = fmaf(bf2f(U.x), K.x, o.x); o.y = fmaf(bf2f(U.y), K.x, o.y);      \
        o.z = fmaf(bf2f(U.z), K.x, o.z); o.w = fmaf(bf2f(U.w), K.x, o.w);      \
        den += K.x;                                                            \
    }

// ---------------- edge aggregation (CSR gather) + normalize + fused transpose ----
__global__ __launch_bounds__(512) void k_agg_t(const ushort* __restrict__ fo,
                                               const float* __restrict__ nw,
                                               const int* __restrict__ rowptr,
                                               const float2* __restrict__ ka2,
                                               float* __restrict__ out) {
    __shared__ float t[OUT][65];
    int tid = threadIdx.x;
    int cg4 = (tid & 31) * 4;
    int s = tid >> 5;                // 0..15
    int n0 = blockIdx.x * 64;        // flat node over B*N
    int b = n0 >> 14, ncol0 = n0 & (N - 1);
    const ushort* fob = fo + (size_t)b * N * OUT;
    for (int g = 0; g < 4; ++g) {
        int nl = g * 16 + s;
        int n = n0 + nl;
        int base = rowptr[n], cnt = rowptr[n + 1] - base;
        float4 o = make_float4(0.f, 0.f, 0.f, 0.f);
        float den = 0.f;
        int i = 0;
        for (; i + 4 <= cnt; i += 4) {
            float2 k0 = ka2[base + i];
            float2 k1 = ka2[base + i + 1];
            float2 k2 = ka2[base + i + 2];
            float2 k3 = ka2[base + i + 3];
            ushort4 u0 = *(const ushort4*)(fob + (size_t)__float_as_int(k0.y) * OUT + cg4);
            ushort4 u1 = *(const ushort4*)(fob + (size_t)__float_as_int(k1.y) * OUT + cg4);
            ushort4 u2 = *(const ushort4*)(fob + (size_t)__float_as_int(k2.y) * OUT + cg4);
            ushort4 u3 = *(const ushort4*)(fob + (size_t)__float_as_int(k3.y) * OUT + cg4);
            AGG_FMA(k0, u0);
            AGG_FMA(k1, u1);
            AGG_FMA(k2, u2);
            AGG_FMA(k3, u3);
        }
        for (; i < cnt; ++i) {
            float2 k0 = ka2[base + i];
            ushort4 u0 = *(const ushort4*)(fob + (size_t)__float_as_int(k0.y) * OUT + cg4);
            AGG_FMA(k0, u0);
        }
        float wn = nw[n];  // self edge: d=0 -> kern = nw[n]
        ushort4 uf = *(const ushort4*)(fo + (size_t)n * OUT + cg4);
        float inv = 1.f / (den + wn);
        t[cg4 + 0][nl] = (o.x + bf2f(uf.x) * wn) * inv;
        t[cg4 + 1][nl] = (o.y + bf2f(uf.y) * wn) * inv;
        t[cg4 + 2][nl] = (o.z + bf2f(uf.z) * wn) * inv;
        t[cg4 + 3][nl] = (o.w + bf2f(uf.w) * wn) * inv;
    }
    __syncthreads();
    #pragma unroll
    for (int i = 0; i < 16; ++i) {
        int idx = tid + i * 512;
        int o = idx >> 6, nl = idx & 63;  // nl fastest -> coalesced writes
        out[((size_t)b * OUT + o) * N + ncol0 + nl] = t[o][nl];
    }
}

extern "C" void kernel_launch(void* const* d_in, const int* in_sizes, int n_in,
                              void* d_out, int out_size, void* d_ws, size_t ws_size,
                              hipStream_t stream) {
    const float* f     = (const float*)d_in[0];
    const float* nodes = (const float*)d_in[1];
    const float* nw    = (const float*)d_in[2];
    const int*   ei    = (const int*)d_in[3];
    const float* egw   = (const float*)d_in[4];
    const float* W1    = (const float*)d_in[5];
    const float* b1    = (const float*)d_in[6];
    const float* W2    = (const float*)d_in[7];
    const float* b2    = (const float*)d_in[8];
    const float* L     = (const float*)d_in[9];
    const float* cb    = (const float*)d_in[10];
    float* out = (float*)d_out;

    char* ws = (char*)d_ws;
    auto alloc = [&](size_t bytes) {
        void* p = ws;
        ws += (bytes + 255) & ~(size_t)255;
        return p;
    };
    ushort* fT     = (ushort*)alloc((size_t)B * N * C * 2);
    ushort* fo     = (ushort*)alloc((size_t)B * N * OUT * 2);
    ushort* W1p    = (ushort*)alloc((size_t)MID * K1 * 2);
    ushort* W2p    = (ushort*)alloc((size_t)OUT * MID * 2);
    float*  Sig    = (float*)alloc(16 * 4);
    int*    deg    = (int*)alloc((size_t)B * N * 4);
    int*    cursor = (int*)alloc((size_t)B * N * 4);
    int*    rowptr = (int*)alloc(((size_t)B * N + 4) * 4);
    int*    bsum   = (int*)alloc(64 * 4);
    int*    perm   = (int*)alloc((size_t)B * E * 4);
    float4* egwp   = (float4*)alloc((size_t)B * E * 16);
    float2* ka2    = (float2*)alloc((size_t)B * E * 8);

    hipMemsetAsync(deg, 0, (size_t)B * N * 4, stream);
    hipMemsetAsync(cursor, 0, (size_t)B * N * 4, stream);

    k_prep<<<1, 256, 0, stream>>>(W1, W2, L, W1p, W2p, Sig);
    k_transpose<<<dim3(N / 32, C / 32, B), dim3(32, 8), 0, stream>>>(f, fT);
    k_count<<<(B * E) / 256, 256, 0, stream>>>((const int2*)ei, deg);
    k_scan1<<<64, 256, 0, stream>>>((const int4*)deg, rowptr, bsum);
    k_scan2<<<1, 64, 0, stream>>>(bsum, rowptr);
    k_scan3<<<64, 256, 0, stream>>>((int4*)rowptr, bsum);
    k_fill_perm<<<(B * E) / 256, 256, 0, stream>>>((const int2*)ei, rowptr, cursor,
                                                   perm);
    k_fill_expand<<<(B * E) / 256, 256, 0, stream>>>(perm, (const int2*)ei, egw,
                                                     nodes, nw, Sig, cb, egwp, ka2);
    k_grad_mlp<<<(B * N) / NT, 512, 0, stream>>>(fT, rowptr, egwp, W1p, b1, W2p,
                                                 b2, fo);
    k_agg_t<<<(B * N) / 64, 512, 0, stream>>>(fo, nw, rowptr, ka2, out);
}

// Round 6
// 219.078 us; speedup vs baseline: 11.2750x; 1.0323x over previous
//
#include <hip/hip_runtime.h>
#include <hip/hip_bf16.h>

// Problem constants
static constexpr int B   = 4;
static constexpr int N   = 16384;   // 2^14
static constexpr int E   = 131072;  // 2^17
static constexpr int C   = 128;
static constexpr int ND  = 3;
static constexpr int MID = 128;
static constexpr int OUT = 128;
static constexpr int K1  = C * ND;  // 384
static constexpr int NT  = 32;      // nodes per block in fused grad+MLP
static constexpr int K1P = 392;     // padded LDS row (2-way max bank conflict)

typedef __attribute__((ext_vector_type(8))) short bf16x8;
typedef __attribute__((ext_vector_type(4))) float f32x4;

__device__ __forceinline__ ushort f2bf(float x) {
    union { float f; unsigned u; } v; v.f = x;
    return (ushort)((v.u + 0x7fffu + ((v.u >> 16) & 1u)) >> 16);  // RNE
}
__device__ __forceinline__ float bf2f(ushort u) {
    union { unsigned u; float f; } v; v.u = (unsigned)u << 16;
    return v.f;
}

// ---------------- prep: W1/W2 -> bf16 MFMA B-fragment order; Sigma = L L^T ----
// B-frag for 16x16x32: lane l holds B[k][n], n = nt*16+(l&15), k = t*32+(l>>4)*8+j
// Multi-block grid-stride (was 1-block = 71us on one CU).
__global__ void k_prep(const float* __restrict__ W1, const float* __restrict__ W2,
                       const float* __restrict__ L, ushort* __restrict__ W1p,
                       ushort* __restrict__ W2p, float* __restrict__ Sig) {
    int gid = blockIdx.x * 256 + threadIdx.x;
    for (int i = gid; i < 8 * 12 * 64 * 8; i += 64 * 256) {
        int j = i & 7, l = (i >> 3) & 63, t = (i >> 9) % 12, nt = (i >> 9) / 12;
        int n = nt * 16 + (l & 15);
        int k = t * 32 + ((l >> 4) & 3) * 8 + j;
        W1p[i] = f2bf(W1[n * K1 + k]);
    }
    for (int i = gid; i < 8 * 4 * 64 * 8; i += 64 * 256) {
        int j = i & 7, l = (i >> 3) & 63, t = (i >> 9) % 4, nt = (i >> 9) / 4;
        int n = nt * 16 + (l & 15);
        int k = t * 32 + ((l >> 4) & 3) * 8 + j;
        W2p[i] = f2bf(W2[n * MID + k]);
    }
    if (gid < 9) {
        int i = gid / 3, j = gid % 3;
        Sig[gid] = L[i * 3 + 0] * L[j * 3 + 0] + L[i * 3 + 1] * L[j * 3 + 1] +
                   L[i * 3 + 2] * L[j * 3 + 2];
    }
}

// ---------------- transpose f (B,C,N) f32 -> fT (B,N,C) bf16 ----------------
__global__ void k_transpose(const float* __restrict__ f, ushort* __restrict__ fT) {
    __shared__ float tile[32][33];
    int b = blockIdx.z;
    int n0 = blockIdx.x * 32, c0 = blockIdx.y * 32;
    const float* fb = f + (size_t)b * C * N;
    ushort* fTb = fT + (size_t)b * N * C;
    int tx = threadIdx.x, ty = threadIdx.y;  // (32,8)
    #pragma unroll
    for (int i = 0; i < 32; i += 8)
        tile[ty + i][tx] = fb[(size_t)(c0 + ty + i) * N + n0 + tx];
    __syncthreads();
    #pragma unroll
    for (int i = 0; i < 32; i += 8)
        fTb[(size_t)(n0 + ty + i) * C + c0 + tx] = f2bf(tile[tx][ty + i]);
}

// ---------------- CSR build: count degrees by target ----------------
__global__ void k_count(const int2* __restrict__ ei2, int* __restrict__ deg) {
    int idx = blockIdx.x * 256 + threadIdx.x;  // 0..B*E-1
    int b = idx >> 17;
    int tgt = ei2[idx].y;
    atomicAdd(&deg[b * N + tgt], 1);
}

// ---------------- hierarchical exclusive scan over 65536 ints ----------------
__global__ void k_scan1(const int4* __restrict__ degv, int* __restrict__ rowptr,
                        int* __restrict__ bsum) {
    __shared__ int s[256];
    int blk = blockIdx.x, t = threadIdx.x;
    int4 d = degv[blk * 256 + t];
    s[t] = d.x + d.y + d.z + d.w;
    __syncthreads();
    for (int off = 1; off < 256; off <<= 1) {
        int v = s[t];
        int u = (t >= off) ? s[t - off] : 0;
        __syncthreads();
        s[t] = v + u;
        __syncthreads();
    }
    int excl = (t == 0) ? 0 : s[t - 1];
    if (t == 255) bsum[blk] = s[255];
    int4 w;
    w.x = excl;
    w.y = excl + d.x;
    w.z = w.y + d.y;
    w.w = w.z + d.z;
    ((int4*)rowptr)[blk * 256 + t] = w;
}

__global__ void k_scan2(int* __restrict__ bsum, int* __restrict__ rowptr) {
    __shared__ int s[64];
    int t = threadIdx.x;  // 64
    s[t] = bsum[t];
    __syncthreads();
    for (int off = 1; off < 64; off <<= 1) {
        int v = s[t];
        int u = (t >= off) ? s[t - off] : 0;
        __syncthreads();
        s[t] = v + u;
        __syncthreads();
    }
    bsum[t] = (t == 0) ? 0 : s[t - 1];
    if (t == 63) rowptr[B * N] = s[63];
}

__global__ void k_scan3(int4* __restrict__ rowv, const int* __restrict__ bsum) {
    int i = blockIdx.x * 256 + threadIdx.x;  // 0..16383 (int4 index)
    int add = bsum[i >> 8];                  // 256 int4 per scan1 block
    int4 v = rowv[i];
    v.x += add; v.y += add; v.z += add; v.w += add;
    rowv[i] = v;
}

// ---------------- CSR fill pass 1: scatter edge id (4B) ----------------
__global__ void k_fill_perm(const int2* __restrict__ ei2,
                            const int* __restrict__ rowptr,
                            int* __restrict__ cursor, int* __restrict__ perm) {
    int idx = blockIdx.x * 256 + threadIdx.x;
    int b = idx >> 17;
    int tgt = ei2[idx].y;
    int bn = b * N + tgt;
    int pos = atomicAdd(&cursor[bn], 1);
    perm[rowptr[bn] + pos] = idx;
}

// ---------------- CSR fill pass 2: coalesced expand (egwp, ka2) ----------------
__global__ void k_fill_expand(const int* __restrict__ perm,
                              const int2* __restrict__ ei2,
                              const float* __restrict__ egw,
                              const float* __restrict__ nodes,
                              const float* __restrict__ nw,
                              const float* __restrict__ Sig,
                              const float* __restrict__ cb,
                              float4* __restrict__ egwp, float2* __restrict__ ka2) {
    int o = blockIdx.x * 256 + threadIdx.x;
    int idx = perm[o];
    int b = idx >> 17;
    int2 e = ei2[idx];
    int src = e.x, tgt = e.y;
    const float* w = egw + (size_t)idx * ND;
    egwp[o] = make_float4(w[0], w[1], w[2], __int_as_float(src));
    const float* ns = nodes + ((size_t)b * N + src) * ND;
    const float* nt = nodes + ((size_t)b * N + tgt) * ND;
    float d0 = ns[0] - nt[0], d1 = ns[1] - nt[1], d2 = ns[2] - nt[2];
    float q = d0 * (Sig[0] * d0 + Sig[1] * d1 + Sig[2] * d2) +
              d1 * (Sig[3] * d0 + Sig[4] * d1 + Sig[5] * d2) +
              d2 * (Sig[6] * d0 + Sig[7] * d1 + Sig[8] * d2) +
              d0 * cb[0] + d1 * cb[1] + d2 * cb[2];
    ka2[o] = make_float2(nw[(size_t)b * N + src] * expf(-q), __int_as_float(src));
}

#define EDGE_FMA(W, U)                                                         \
    {                                                                          \
        float dx = bf2f(U.x) - ft.x, dy = bf2f(U.y) - ft.y,                    \
              dz = bf2f(U.z) - ft.z, dw = bf2f(U.w) - ft.w;                    \
        a0.x = fmaf(dx, W.x, a0.x); a0.y = fmaf(dy, W.x, a0.y);                \
        a0.z = fmaf(dz, W.x, a0.z); a0.w = fmaf(dw, W.x, a0.w);                \
        a1.x = fmaf(dx, W.y, a1.x); a1.y = fmaf(dy, W.y, a1.y);                \
        a1.z = fmaf(dz, W.y, a1.z); a1.w = fmaf(dw, W.y, a1.w);                \
        a2.x = fmaf(dx, W.z, a2.x); a2.y = fmaf(dy, W.z, a2.y);                \
        a2.z = fmaf(dz, W.z, a2.z); a2.w = fmaf(dw, W.z, a2.w);                \
    }

// ---------------- fused gradient gather (VALU) + pointwise MLP (MFMA) --------
// NT=32: LDS 25088B -> 4 blocks x 8 waves = 32 waves/CU (wave-capped, 100%).
// Gather: 16 slots x 32 lanes, 2 nodes/slot-lane, unroll-4.
// MFMA: 8 waves = 2 mtiles (mt=wv&1) x 4 nt-pairs (nh=wv>>1, nt=nh*2+q).
__global__ __launch_bounds__(512, 8) void k_grad_mlp(
    const ushort* __restrict__ fT, const int* __restrict__ rowptr,
    const float4* __restrict__ egwp, const ushort* __restrict__ W1p,
    const float* __restrict__ b1, const ushort* __restrict__ W2p,
    const float* __restrict__ b2, ushort* __restrict__ fo) {
    __shared__ ushort g_s[NT][K1P];  // 25088 B
    int tid = threadIdx.x;
    int n0 = blockIdx.x * NT;  // flat node over B*N

    {  // ---- gather phase ----
        int cg = tid & 31, s = tid >> 5;  // 32 channel-groups x 16 node slots
        int cg4 = cg * 4;
        for (int jj = 0; jj < NT; jj += 16) {
            int j = jj + s;
            int n = n0 + j;
            const ushort* fTb = fT + (size_t)(n >> 14) * N * C;  // batch base
            float4 ft;
            {
                ushort4 u = *(const ushort4*)(fT + (size_t)n * C + cg4);
                ft = make_float4(bf2f(u.x), bf2f(u.y), bf2f(u.z), bf2f(u.w));
            }
            int base = rowptr[n], cnt = rowptr[n + 1] - base;
            float4 a0 = make_float4(0.f, 0.f, 0.f, 0.f), a1 = a0, a2 = a0;
            int i = 0;
            for (; i + 4 <= cnt; i += 4) {
                float4 w0 = egwp[base + i];
                float4 w1 = egwp[base + i + 1];
                float4 w2 = egwp[base + i + 2];
                float4 w3 = egwp[base + i + 3];
                ushort4 u0 = *(const ushort4*)(fTb + (size_t)__float_as_int(w0.w) * C + cg4);
                ushort4 u1 = *(const ushort4*)(fTb + (size_t)__float_as_int(w1.w) * C + cg4);
                ushort4 u2 = *(const ushort4*)(fTb + (size_t)__float_as_int(w2.w) * C + cg4);
                ushort4 u3 = *(const ushort4*)(fTb + (size_t)__float_as_int(w3.w) * C + cg4);
                EDGE_FMA(w0, u0);
                EDGE_FMA(w1, u1);
                EDGE_FMA(w2, u2);
                EDGE_FMA(w3, u3);
            }
            for (; i < cnt; ++i) {
                float4 w0 = egwp[base + i];
                ushort4 u0 = *(const ushort4*)(fTb + (size_t)__float_as_int(w0.w) * C + cg4);
                EDGE_FMA(w0, u0);
            }
            // g[k], k = c*3+d, c = 4cg+u -> k = 12cg+3u+d: 12 contiguous bf16
            unsigned p0 = (unsigned)f2bf(a0.x) | ((unsigned)f2bf(a1.x) << 16);
            unsigned p1 = (unsigned)f2bf(a2.x) | ((unsigned)f2bf(a0.y) << 16);
            unsigned p2 = (unsigned)f2bf(a1.y) | ((unsigned)f2bf(a2.y) << 16);
            unsigned p3 = (unsigned)f2bf(a0.z) | ((unsigned)f2bf(a1.z) << 16);
            unsigned p4 = (unsigned)f2bf(a2.z) | ((unsigned)f2bf(a0.w) << 16);
            unsigned p5 = (unsigned)f2bf(a1.w) | ((unsigned)f2bf(a2.w) << 16);
            uint2* dst = (uint2*)&g_s[j][cg * 12];
            dst[0] = make_uint2(p0, p1);
            dst[1] = make_uint2(p2, p3);
            dst[2] = make_uint2(p4, p5);
        }
    }
    __syncthreads();

    // ---- MFMA phase: 8 waves = 2 mtiles x 4 nt-pairs ----
    int wv = tid >> 6, ln = tid & 63, lr = ln & 15, lh = ln >> 4;
    int mt = wv & 1, nh = wv >> 1;
    bf16x8 a[12];  // A-frags for this wave's 16-node mtile, all K
    {
        const ushort* grow = &g_s[mt * 16 + lr][0];
        #pragma unroll
        for (int t = 0; t < 12; ++t)
            a[t] = *(const bf16x8*)(grow + t * 32 + lh * 8);
    }
    __syncthreads();  // all A-reads done before h_s (aliasing g_s) is written

    ushort(*h_s)[136] = (ushort(*)[136]) & g_s[0][0];  // 8704 B alias
    const bf16x8* W1f = (const bf16x8*)W1p;
    #pragma unroll
    for (int q = 0; q < 2; ++q) {
        int nt = nh * 2 + q;
        float bb = b1[nt * 16 + lr];
        f32x4 c = {bb, bb, bb, bb};
        #pragma unroll
        for (int t = 0; t < 12; ++t)
            c = __builtin_amdgcn_mfma_f32_16x16x32_bf16(
                a[t], W1f[(nt * 12 + t) * 64 + ln], c, 0, 0, 0);
        #pragma unroll
        for (int r = 0; r < 4; ++r) {
            float x = c[r];
            x = 0.5f * x * (1.0f + erff(x * 0.70710678118654752f));
            h_s[mt * 16 + lh * 4 + r][nt * 16 + lr] = f2bf(x);  // row=node, col=mid
        }
    }
    __syncthreads();  // all nt-pairs of h complete

    bf16x8 a2[4];
    {
        const ushort* hrow = &h_s[mt * 16 + lr][0];
        #pragma unroll
        for (int t = 0; t < 4; ++t)
            a2[t] = *(const bf16x8*)(hrow + t * 32 + lh * 8);
    }
    const bf16x8* W2f = (const bf16x8*)W2p;
    #pragma unroll
    for (int q = 0; q < 2; ++q) {
        int nt = nh * 2 + q;
        float bb = b2[nt * 16 + lr];
        f32x4 c = {bb, bb, bb, bb};
        #pragma unroll
        for (int t = 0; t < 4; ++t)
            c = __builtin_amdgcn_mfma_f32_16x16x32_bf16(
                a2[t], W2f[(nt * 4 + t) * 64 + ln], c, 0, 0, 0);
        #pragma unroll
        for (int r = 0; r < 4; ++r)
            fo[(size_t)(n0 + mt * 16 + lh * 4 + r) * OUT + nt * 16 + lr] = f2bf(c[r]);
    }
}

#define AGG_FMA(K, U)                                                          \
    {                                                                          \
        o.x = fmaf(bf2f(U.x), K.x, o.x); o.y = fmaf(bf2f(U.y), K.x, o.y);      \
        o.z = fmaf(bf2f(U.z), K.x, o.z); o.w = fmaf(bf2f(U.w), K.x, o.w);      \
        den += K.x;                                                            \
    }

// ---------------- edge aggregation (CSR gather) + normalize + fused transpose ----
__global__ __launch_bounds__(512) void k_agg_t(const ushort* __restrict__ fo,
                                               const float* __restrict__ nw,
                                               const int* __restrict__ rowptr,
                                               const float2* __restrict__ ka2,
                                               float* __restrict__ out) {
    __shared__ float t[OUT][65];
    int tid = threadIdx.x;
    int cg4 = (tid & 31) * 4;
    int s = tid >> 5;                // 0..15
    int n0 = blockIdx.x * 64;        // flat node over B*N
    int b = n0 >> 14, ncol0 = n0 & (N - 1);
    const ushort* fob = fo + (size_t)b * N * OUT;
    for (int g = 0; g < 4; ++g) {
        int nl = g * 16 + s;
        int n = n0 + nl;
        int base = rowptr[n], cnt = rowptr[n + 1] - base;
        float4 o = make_float4(0.f, 0.f, 0.f, 0.f);
        float den = 0.f;
        int i = 0;
        for (; i + 4 <= cnt; i += 4) {
            float2 k0 = ka2[base + i];
            float2 k1 = ka2[base + i + 1];
            float2 k2 = ka2[base + i + 2];
            float2 k3 = ka2[base + i + 3];
            ushort4 u0 = *(const ushort4*)(fob + (size_t)__float_as_int(k0.y) * OUT + cg4);
            ushort4 u1 = *(const ushort4*)(fob + (size_t)__float_as_int(k1.y) * OUT + cg4);
            ushort4 u2 = *(const ushort4*)(fob + (size_t)__float_as_int(k2.y) * OUT + cg4);
            ushort4 u3 = *(const ushort4*)(fob + (size_t)__float_as_int(k3.y) * OUT + cg4);
            AGG_FMA(k0, u0);
            AGG_FMA(k1, u1);
            AGG_FMA(k2, u2);
            AGG_FMA(k3, u3);
        }
        for (; i < cnt; ++i) {
            float2 k0 = ka2[base + i];
            ushort4 u0 = *(const ushort4*)(fob + (size_t)__float_as_int(k0.y) * OUT + cg4);
            AGG_FMA(k0, u0);
        }
        float wn = nw[n];  // self edge: d=0 -> kern = nw[n]
        ushort4 uf = *(const ushort4*)(fo + (size_t)n * OUT + cg4);
        float inv = 1.f / (den + wn);
        t[cg4 + 0][nl] = (o.x + bf2f(uf.x) * wn) * inv;
        t[cg4 + 1][nl] = (o.y + bf2f(uf.y) * wn) * inv;
        t[cg4 + 2][nl] = (o.z + bf2f(uf.z) * wn) * inv;
        t[cg4 + 3][nl] = (o.w + bf2f(uf.w) * wn) * inv;
    }
    __syncthreads();
    #pragma unroll
    for (int i = 0; i < 16; ++i) {
        int idx = tid + i * 512;
        int o = idx >> 6, nl = idx & 63;  // nl fastest -> coalesced writes
        out[((size_t)b * OUT + o) * N + ncol0 + nl] = t[o][nl];
    }
}

extern "C" void kernel_launch(void* const* d_in, const int* in_sizes, int n_in,
                              void* d_out, int out_size, void* d_ws, size_t ws_size,
                              hipStream_t stream) {
    const float* f     = (const float*)d_in[0];
    const float* nodes = (const float*)d_in[1];
    const float* nw    = (const float*)d_in[2];
    const int*   ei    = (const int*)d_in[3];
    const float* egw   = (const float*)d_in[4];
    const float* W1    = (const float*)d_in[5];
    const float* b1    = (const float*)d_in[6];
    const float* W2    = (const float*)d_in[7];
    const float* b2    = (const float*)d_in[8];
    const float* L     = (const float*)d_in[9];
    const float* cb    = (const float*)d_in[10];
    float* out = (float*)d_out;

    char* ws = (char*)d_ws;
    auto alloc = [&](size_t bytes) {
        void* p = ws;
        ws += (bytes + 255) & ~(size_t)255;
        return p;
    };
    ushort* fT     = (ushort*)alloc((size_t)B * N * C * 2);
    ushort* fo     = (ushort*)alloc((size_t)B * N * OUT * 2);
    ushort* W1p    = (ushort*)alloc((size_t)MID * K1 * 2);
    ushort* W2p    = (ushort*)alloc((size_t)OUT * MID * 2);
    float*  Sig    = (float*)alloc(16 * 4);
    int*    deg    = (int*)alloc((size_t)B * N * 4);
    int*    cursor = (int*)alloc((size_t)B * N * 4);
    int*    rowptr = (int*)alloc(((size_t)B * N + 4) * 4);
    int*    bsum   = (int*)alloc(64 * 4);
    int*    perm   = (int*)alloc((size_t)B * E * 4);
    float4* egwp   = (float4*)alloc((size_t)B * E * 16);
    float2* ka2    = (float2*)alloc((size_t)B * E * 8);

    hipMemsetAsync(deg, 0, (size_t)B * N * 4, stream);
    hipMemsetAsync(cursor, 0, (size_t)B * N * 4, stream);

    k_prep<<<64, 256, 0, stream>>>(W1, W2, L, W1p, W2p, Sig);
    k_transpose<<<dim3(N / 32, C / 32, B), dim3(32, 8), 0, stream>>>(f, fT);
    k_count<<<(B * E) / 256, 256, 0, stream>>>((const int2*)ei, deg);
    k_scan1<<<64, 256, 0, stream>>>((const int4*)deg, rowptr, bsum);
    k_scan2<<<1, 64, 0, stream>>>(bsum, rowptr);
    k_scan3<<<64, 256, 0, stream>>>((int4*)rowptr, bsum);
    k_fill_perm<<<(B * E) / 256, 256, 0, stream>>>((const int2*)ei, rowptr, cursor,
                                                   perm);
    k_fill_expand<<<(B * E) / 256, 256, 0, stream>>>(perm, (const int2*)ei, egw,
                                                     nodes, nw, Sig, cb, egwp, ka2);
    k_grad_mlp<<<(B * N) / NT, 512, 0, stream>>>(fT, rowptr, egwp, W1p, b1, W2p,
                                                 b2, fo);
    k_agg_t<<<(B * N) / 64, 512, 0, stream>>>(fo, nw, rowptr, ka2, out);
}

// Round 7
// 171.573 us; speedup vs baseline: 14.3968x; 1.2769x over previous
//
#include <hip/hip_runtime.h>
#include <hip/hip_bf16.h>

// Problem constants
static constexpr int B   = 4;
static constexpr int N   = 16384;   // 2^14
static constexpr int E   = 131072;  // 2^17
static constexpr int C   = 128;
static constexpr int ND  = 3;
static constexpr int MID = 128;
static constexpr int OUT = 128;
static constexpr int K1  = C * ND;  // 384
static constexpr int NT  = 32;      // nodes per block in fused grad+MLP
static constexpr int K1P = 392;     // padded LDS row (2-way max bank conflict)

typedef __attribute__((ext_vector_type(8))) short bf16x8;
typedef __attribute__((ext_vector_type(4))) float f32x4;

__device__ __forceinline__ ushort f2bf(float x) {
    union { float f; unsigned u; } v; v.f = x;
    return (ushort)((v.u + 0x7fffu + ((v.u >> 16) & 1u)) >> 16);  // RNE
}
__device__ __forceinline__ float bf2f(ushort u) {
    union { unsigned u; float f; } v; v.u = (unsigned)u << 16;
    return v.f;
}

// ---------------- prep: W1/W2 -> bf16 MFMA B-fragment order; Sigma = L L^T ----
// B-frag for 16x16x32: lane l holds B[k][n], n = nt*16+(l&15), k = t*32+(l>>4)*8+j
__global__ void k_prep(const float* __restrict__ W1, const float* __restrict__ W2,
                       const float* __restrict__ L, ushort* __restrict__ W1p,
                       ushort* __restrict__ W2p, float* __restrict__ Sig) {
    int gid = blockIdx.x * 256 + threadIdx.x;
    for (int i = gid; i < 8 * 12 * 64 * 8; i += 64 * 256) {
        int j = i & 7, l = (i >> 3) & 63, t = (i >> 9) % 12, nt = (i >> 9) / 12;
        int n = nt * 16 + (l & 15);
        int k = t * 32 + ((l >> 4) & 3) * 8 + j;
        W1p[i] = f2bf(W1[n * K1 + k]);
    }
    for (int i = gid; i < 8 * 4 * 64 * 8; i += 64 * 256) {
        int j = i & 7, l = (i >> 3) & 63, t = (i >> 9) % 4, nt = (i >> 9) / 4;
        int n = nt * 16 + (l & 15);
        int k = t * 32 + ((l >> 4) & 3) * 8 + j;
        W2p[i] = f2bf(W2[n * MID + k]);
    }
    if (gid < 9) {
        int i = gid / 3, j = gid % 3;
        Sig[gid] = L[i * 3 + 0] * L[j * 3 + 0] + L[i * 3 + 1] * L[j * 3 + 1] +
                   L[i * 3 + 2] * L[j * 3 + 2];
    }
}

// ---------------- transpose f (B,C,N) f32 -> fT (B,N,C) bf16 ----------------
__global__ void k_transpose(const float* __restrict__ f, ushort* __restrict__ fT) {
    __shared__ float tile[32][33];
    int b = blockIdx.z;
    int n0 = blockIdx.x * 32, c0 = blockIdx.y * 32;
    const float* fb = f + (size_t)b * C * N;
    ushort* fTb = fT + (size_t)b * N * C;
    int tx = threadIdx.x, ty = threadIdx.y;  // (32,8)
    #pragma unroll
    for (int i = 0; i < 32; i += 8)
        tile[ty + i][tx] = fb[(size_t)(c0 + ty + i) * N + n0 + tx];
    __syncthreads();
    #pragma unroll
    for (int i = 0; i < 32; i += 8)
        fTb[(size_t)(n0 + ty + i) * C + c0 + tx] = f2bf(tile[tx][ty + i]);
}

// ---------------- CSR build: count degrees by target ----------------
__global__ void k_count(const int2* __restrict__ ei2, int* __restrict__ deg) {
    int idx = blockIdx.x * 256 + threadIdx.x;  // 0..B*E-1
    int b = idx >> 17;
    int tgt = ei2[idx].y;
    atomicAdd(&deg[b * N + tgt], 1);
}

// ---------------- hierarchical exclusive scan over 65536 ints ----------------
__global__ void k_scan1(const int4* __restrict__ degv, int* __restrict__ rowptr,
                        int* __restrict__ bsum) {
    __shared__ int s[256];
    int blk = blockIdx.x, t = threadIdx.x;
    int4 d = degv[blk * 256 + t];
    s[t] = d.x + d.y + d.z + d.w;
    __syncthreads();
    for (int off = 1; off < 256; off <<= 1) {
        int v = s[t];
        int u = (t >= off) ? s[t - off] : 0;
        __syncthreads();
        s[t] = v + u;
        __syncthreads();
    }
    int excl = (t == 0) ? 0 : s[t - 1];
    if (t == 255) bsum[blk] = s[255];
    int4 w;
    w.x = excl;
    w.y = excl + d.x;
    w.z = w.y + d.y;
    w.w = w.z + d.z;
    ((int4*)rowptr)[blk * 256 + t] = w;
}

__global__ void k_scan2(int* __restrict__ bsum, int* __restrict__ rowptr) {
    __shared__ int s[64];
    int t = threadIdx.x;  // 64
    s[t] = bsum[t];
    __syncthreads();
    for (int off = 1; off < 64; off <<= 1) {
        int v = s[t];
        int u = (t >= off) ? s[t - off] : 0;
        __syncthreads();
        s[t] = v + u;
        __syncthreads();
    }
    bsum[t] = (t == 0) ? 0 : s[t - 1];
    if (t == 63) rowptr[B * N] = s[63];
}

__global__ void k_scan3(int4* __restrict__ rowv, const int* __restrict__ bsum) {
    int i = blockIdx.x * 256 + threadIdx.x;  // 0..16383 (int4 index)
    int add = bsum[i >> 8];                  // 256 int4 per scan1 block
    int4 v = rowv[i];
    v.x += add; v.y += add; v.z += add; v.w += add;
    rowv[i] = v;
}

// ---------------- CSR fill pass 1: scatter edge id (4B) ----------------
__global__ void k_fill_perm(const int2* __restrict__ ei2,
                            const int* __restrict__ rowptr,
                            int* __restrict__ cursor, int* __restrict__ perm) {
    int idx = blockIdx.x * 256 + threadIdx.x;
    int b = idx >> 17;
    int tgt = ei2[idx].y;
    int bn = b * N + tgt;
    int pos = atomicAdd(&cursor[bn], 1);
    perm[rowptr[bn] + pos] = idx;
}

// ---------------- CSR fill pass 2: coalesced expand (egwp, ka2) ----------------
__global__ void k_fill_expand(const int* __restrict__ perm,
                              const int2* __restrict__ ei2,
                              const float* __restrict__ egw,
                              const float* __restrict__ nodes,
                              const float* __restrict__ nw,
                              const float* __restrict__ Sig,
                              const float* __restrict__ cb,
                              float4* __restrict__ egwp, float2* __restrict__ ka2) {
    int o = blockIdx.x * 256 + threadIdx.x;
    int idx = perm[o];
    int b = idx >> 17;
    int2 e = ei2[idx];
    int src = e.x, tgt = e.y;
    const float* w = egw + (size_t)idx * ND;
    egwp[o] = make_float4(w[0], w[1], w[2], __int_as_float(src));
    const float* ns = nodes + ((size_t)b * N + src) * ND;
    const float* nt = nodes + ((size_t)b * N + tgt) * ND;
    float d0 = ns[0] - nt[0], d1 = ns[1] - nt[1], d2 = ns[2] - nt[2];
    float q = d0 * (Sig[0] * d0 + Sig[1] * d1 + Sig[2] * d2) +
              d1 * (Sig[3] * d0 + Sig[4] * d1 + Sig[5] * d2) +
              d2 * (Sig[6] * d0 + Sig[7] * d1 + Sig[8] * d2) +
              d0 * cb[0] + d1 * cb[1] + d2 * cb[2];
    ka2[o] = make_float2(nw[(size_t)b * N + src] * expf(-q), __int_as_float(src));
}

#define EDGE_FMA(W, U)                                                         \
    {                                                                          \
        float dx = bf2f(U.x) - ft.x, dy = bf2f(U.y) - ft.y,                    \
              dz = bf2f(U.z) - ft.z, dw = bf2f(U.w) - ft.w;                    \
        a0.x = fmaf(dx, W.x, a0.x); a0.y = fmaf(dy, W.x, a0.y);                \
        a0.z = fmaf(dz, W.x, a0.z); a0.w = fmaf(dw, W.x, a0.w);                \
        a1.x = fmaf(dx, W.y, a1.x); a1.y = fmaf(dy, W.y, a1.y);                \
        a1.z = fmaf(dz, W.y, a1.z); a1.w = fmaf(dw, W.y, a1.w);                \
        a2.x = fmaf(dx, W.z, a2.x); a2.y = fmaf(dy, W.z, a2.y);                \
        a2.z = fmaf(dz, W.z, a2.z); a2.w = fmaf(dw, W.z, a2.w);                \
    }

// ---------------- fused gradient gather (VALU) + pointwise MLP (MFMA) --------
// NT=32, LDS 25088B. launch_bounds (512,5): proven to give ~48 VGPR, no spill
// (round 6's (512,8) forced VGPR=32 -> 220MB of scratch spill traffic).
// Occupancy: LDS cap 6 blk/CU, wave cap 4 blk (32 waves), VGPR 48 -> 4 blk/CU.
__global__ __launch_bounds__(512, 5) void k_grad_mlp(
    const ushort* __restrict__ fT, const int* __restrict__ rowptr,
    const float4* __restrict__ egwp, const ushort* __restrict__ W1p,
    const float* __restrict__ b1, const ushort* __restrict__ W2p,
    const float* __restrict__ b2, ushort* __restrict__ fo) {
    __shared__ ushort g_s[NT][K1P];  // 25088 B
    int tid = threadIdx.x;
    int n0 = blockIdx.x * NT;  // flat node over B*N

    {  // ---- gather phase ----
        int cg = tid & 31, s = tid >> 5;  // 32 channel-groups x 16 node slots
        int cg4 = cg * 4;
        for (int jj = 0; jj < NT; jj += 16) {
            int j = jj + s;
            int n = n0 + j;
            const ushort* fTb = fT + (size_t)(n >> 14) * N * C;  // batch base
            float4 ft;
            {
                ushort4 u = *(const ushort4*)(fT + (size_t)n * C + cg4);
                ft = make_float4(bf2f(u.x), bf2f(u.y), bf2f(u.z), bf2f(u.w));
            }
            int base = rowptr[n], cnt = rowptr[n + 1] - base;
            float4 a0 = make_float4(0.f, 0.f, 0.f, 0.f), a1 = a0, a2 = a0;
            int i = 0;
            for (; i + 4 <= cnt; i += 4) {
                float4 w0 = egwp[base + i];
                float4 w1 = egwp[base + i + 1];
                float4 w2 = egwp[base + i + 2];
                float4 w3 = egwp[base + i + 3];
                ushort4 u0 = *(const ushort4*)(fTb + (size_t)__float_as_int(w0.w) * C + cg4);
                ushort4 u1 = *(const ushort4*)(fTb + (size_t)__float_as_int(w1.w) * C + cg4);
                ushort4 u2 = *(const ushort4*)(fTb + (size_t)__float_as_int(w2.w) * C + cg4);
                ushort4 u3 = *(const ushort4*)(fTb + (size_t)__float_as_int(w3.w) * C + cg4);
                EDGE_FMA(w0, u0);
                EDGE_FMA(w1, u1);
                EDGE_FMA(w2, u2);
                EDGE_FMA(w3, u3);
            }
            for (; i < cnt; ++i) {
                float4 w0 = egwp[base + i];
                ushort4 u0 = *(const ushort4*)(fTb + (size_t)__float_as_int(w0.w) * C + cg4);
                EDGE_FMA(w0, u0);
            }
            // g[k], k = c*3+d, c = 4cg+u -> k = 12cg+3u+d: 12 contiguous bf16
            unsigned p0 = (unsigned)f2bf(a0.x) | ((unsigned)f2bf(a1.x) << 16);
            unsigned p1 = (unsigned)f2bf(a2.x) | ((unsigned)f2bf(a0.y) << 16);
            unsigned p2 = (unsigned)f2bf(a1.y) | ((unsigned)f2bf(a2.y) << 16);
            unsigned p3 = (unsigned)f2bf(a0.z) | ((unsigned)f2bf(a1.z) << 16);
            unsigned p4 = (unsigned)f2bf(a2.z) | ((unsigned)f2bf(a0.w) << 16);
            unsigned p5 = (unsigned)f2bf(a1.w) | ((unsigned)f2bf(a2.w) << 16);
            uint2* dst = (uint2*)&g_s[j][cg * 12];
            dst[0] = make_uint2(p0, p1);
            dst[1] = make_uint2(p2, p3);
            dst[2] = make_uint2(p4, p5);
        }
    }
    __syncthreads();

    // ---- MFMA phase: 8 waves = 2 mtiles x 4 nt-pairs ----
    int wv = tid >> 6, ln = tid & 63, lr = ln & 15, lh = ln >> 4;
    int mt = wv & 1, nh = wv >> 1;
    bf16x8 a[12];  // A-frags for this wave's 16-node mtile, all K
    {
        const ushort* grow = &g_s[mt * 16 + lr][0];
        #pragma unroll
        for (int t = 0; t < 12; ++t)
            a[t] = *(const bf16x8*)(grow + t * 32 + lh * 8);
    }
    __syncthreads();  // all A-reads done before h_s (aliasing g_s) is written

    ushort(*h_s)[136] = (ushort(*)[136]) & g_s[0][0];  // 8704 B alias
    const bf16x8* W1f = (const bf16x8*)W1p;
    #pragma unroll
    for (int q = 0; q < 2; ++q) {
        int nt = nh * 2 + q;
        float bb = b1[nt * 16 + lr];
        f32x4 c = {bb, bb, bb, bb};
        #pragma unroll
        for (int t = 0; t < 12; ++t)
            c = __builtin_amdgcn_mfma_f32_16x16x32_bf16(
                a[t], W1f[(nt * 12 + t) * 64 + ln], c, 0, 0, 0);
        #pragma unroll
        for (int r = 0; r < 4; ++r) {
            float x = c[r];
            x = 0.5f * x * (1.0f + erff(x * 0.70710678118654752f));
            h_s[mt * 16 + lh * 4 + r][nt * 16 + lr] = f2bf(x);  // row=node, col=mid
        }
    }
    __syncthreads();  // all nt-pairs of h complete

    bf16x8 a2[4];
    {
        const ushort* hrow = &h_s[mt * 16 + lr][0];
        #pragma unroll
        for (int t = 0; t < 4; ++t)
            a2[t] = *(const bf16x8*)(hrow + t * 32 + lh * 8);
    }
    const bf16x8* W2f = (const bf16x8*)W2p;
    #pragma unroll
    for (int q = 0; q < 2; ++q) {
        int nt = nh * 2 + q;
        float bb = b2[nt * 16 + lr];
        f32x4 c = {bb, bb, bb, bb};
        #pragma unroll
        for (int t = 0; t < 4; ++t)
            c = __builtin_amdgcn_mfma_f32_16x16x32_bf16(
                a2[t], W2f[(nt * 4 + t) * 64 + ln], c, 0, 0, 0);
        #pragma unroll
        for (int r = 0; r < 4; ++r)
            fo[(size_t)(n0 + mt * 16 + lh * 4 + r) * OUT + nt * 16 + lr] = f2bf(c[r]);
    }
}

#define AGG_FMA(K, U)                                                          \
    {                                                                          \
        o.x = fmaf(bf2f(U.x), K.x, o.x); o.y = fmaf(bf2f(U.y), K.x, o.y);      \
        o.z = fmaf(bf2f(U.z), K.x, o.z); o.w = fmaf(bf2f(U.w), K.x, o.w);      \
        den += K.x;                                                            \
    }

// ---------------- edge aggregation (CSR gather) + normalize + fused transpose ----
__global__ __launch_bounds__(512, 5) void k_agg_t(const ushort* __restrict__ fo,
                                                  const float* __restrict__ nw,
                                                  const int* __restrict__ rowptr,
                                                  const float2* __restrict__ ka2,
                                                  float* __restrict__ out) {
    __shared__ float t[OUT][65];
    int tid = threadIdx.x;
    int cg4 = (tid & 31) * 4;
    int s = tid >> 5;                // 0..15
    int n0 = blockIdx.x * 64;        // flat node over B*N
    int b = n0 >> 14, ncol0 = n0 & (N - 1);
    const ushort* fob = fo + (size_t)b * N * OUT;
    for (int g = 0; g < 4; ++g) {
        int nl = g * 16 + s;
        int n = n0 + nl;
        int base = rowptr[n], cnt = rowptr[n + 1] - base;
        float4 o = make_float4(0.f, 0.f, 0.f, 0.f);
        float den = 0.f;
        int i = 0;
        for (; i + 4 <= cnt; i += 4) {
            float2 k0 = ka2[base + i];
            float2 k1 = ka2[base + i + 1];
            float2 k2 = ka2[base + i + 2];
            float2 k3 = ka2[base + i + 3];
            ushort4 u0 = *(const ushort4*)(fob + (size_t)__float_as_int(k0.y) * OUT + cg4);
            ushort4 u1 = *(const ushort4*)(fob + (size_t)__float_as_int(k1.y) * OUT + cg4);
            ushort4 u2 = *(const ushort4*)(fob + (size_t)__float_as_int(k2.y) * OUT + cg4);
            ushort4 u3 = *(const ushort4*)(fob + (size_t)__float_as_int(k3.y) * OUT + cg4);
            AGG_FMA(k0, u0);
            AGG_FMA(k1, u1);
            AGG_FMA(k2, u2);
            AGG_FMA(k3, u3);
        }
        for (; i < cnt; ++i) {
            float2 k0 = ka2[base + i];
            ushort4 u0 = *(const ushort4*)(fob + (size_t)__float_as_int(k0.y) * OUT + cg4);
            AGG_FMA(k0, u0);
        }
        float wn = nw[n];  // self edge: d=0 -> kern = nw[n]
        ushort4 uf = *(const ushort4*)(fo + (size_t)n * OUT + cg4);
        float inv = 1.f / (den + wn);
        t[cg4 + 0][nl] = (o.x + bf2f(uf.x) * wn) * inv;
        t[cg4 + 1][nl] = (o.y + bf2f(uf.y) * wn) * inv;
        t[cg4 + 2][nl] = (o.z + bf2f(uf.z) * wn) * inv;
        t[cg4 + 3][nl] = (o.w + bf2f(uf.w) * wn) * inv;
    }
    __syncthreads();
    #pragma unroll
    for (int i = 0; i < 16; ++i) {
        int idx = tid + i * 512;
        int o = idx >> 6, nl = idx & 63;  // nl fastest -> coalesced writes
        out[((size_t)b * OUT + o) * N + ncol0 + nl] = t[o][nl];
    }
}

extern "C" void kernel_launch(void* const* d_in, const int* in_sizes, int n_in,
                              void* d_out, int out_size, void* d_ws, size_t ws_size,
                              hipStream_t stream) {
    const float* f     = (const float*)d_in[0];
    const float* nodes = (const float*)d_in[1];
    const float* nw    = (const float*)d_in[2];
    const int*   ei    = (const int*)d_in[3];
    const float* egw   = (const float*)d_in[4];
    const float* W1    = (const float*)d_in[5];
    const float* b1    = (const float*)d_in[6];
    const float* W2    = (const float*)d_in[7];
    const float* b2    = (const float*)d_in[8];
    const float* L     = (const float*)d_in[9];
    const float* cb    = (const float*)d_in[10];
    float* out = (float*)d_out;

    char* ws = (char*)d_ws;
    auto alloc = [&](size_t bytes) {
        void* p = ws;
        ws += (bytes + 255) & ~(size_t)255;
        return p;
    };
    ushort* fT     = (ushort*)alloc((size_t)B * N * C * 2);
    ushort* fo     = (ushort*)alloc((size_t)B * N * OUT * 2);
    ushort* W1p    = (ushort*)alloc((size_t)MID * K1 * 2);
    ushort* W2p    = (ushort*)alloc((size_t)OUT * MID * 2);
    float*  Sig    = (float*)alloc(16 * 4);
    int*    deg    = (int*)alloc((size_t)B * N * 4);
    int*    cursor = (int*)alloc((size_t)B * N * 4);
    int*    rowptr = (int*)alloc(((size_t)B * N + 4) * 4);
    int*    bsum   = (int*)alloc(64 * 4);
    int*    perm   = (int*)alloc((size_t)B * E * 4);
    float4* egwp   = (float4*)alloc((size_t)B * E * 16);
    float2* ka2    = (float2*)alloc((size_t)B * E * 8);

    hipMemsetAsync(deg, 0, (size_t)B * N * 4, stream);
    hipMemsetAsync(cursor, 0, (size_t)B * N * 4, stream);

    k_prep<<<64, 256, 0, stream>>>(W1, W2, L, W1p, W2p, Sig);
    k_transpose<<<dim3(N / 32, C / 32, B), dim3(32, 8), 0, stream>>>(f, fT);
    k_count<<<(B * E) / 256, 256, 0, stream>>>((const int2*)ei, deg);
    k_scan1<<<64, 256, 0, stream>>>((const int4*)deg, rowptr, bsum);
    k_scan2<<<1, 64, 0, stream>>>(bsum, rowptr);
    k_scan3<<<64, 256, 0, stream>>>((int4*)rowptr, bsum);
    k_fill_perm<<<(B * E) / 256, 256, 0, stream>>>((const int2*)ei, rowptr, cursor,
                                                   perm);
    k_fill_expand<<<(B * E) / 256, 256, 0, stream>>>(perm, (const int2*)ei, egw,
                                                     nodes, nw, Sig, cb, egwp, ka2);
    k_grad_mlp<<<(B * N) / NT, 512, 0, stream>>>(fT, rowptr, egwp, W1p, b1, W2p,
                                                 b2, fo);
    k_agg_t<<<(B * N) / 64, 512, 0, stream>>>(fo, nw, rowptr, ka2, out);
}

// Round 8
// 155.892 us; speedup vs baseline: 15.8450x; 1.1006x over previous
//
#include <hip/hip_runtime.h>
#include <hip/hip_bf16.h>

// Problem constants
static constexpr int B   = 4;
static constexpr int N   = 16384;   // 2^14
static constexpr int E   = 131072;  // 2^17
static constexpr int C   = 128;
static constexpr int ND  = 3;
static constexpr int MID = 128;
static constexpr int OUT = 128;
static constexpr int K1  = C * ND;  // 384
static constexpr int NT  = 32;      // nodes per block in fused grad+MLP
static constexpr int K1P = 392;     // padded LDS row (2-way max bank conflict)

typedef __attribute__((ext_vector_type(8))) short bf16x8;
typedef __attribute__((ext_vector_type(8))) unsigned short ushort8v;
typedef __attribute__((ext_vector_type(4))) float f32x4;

__device__ __forceinline__ ushort f2bf(float x) {
    union { float f; unsigned u; } v; v.f = x;
    return (ushort)((v.u + 0x7fffu + ((v.u >> 16) & 1u)) >> 16);  // RNE
}
__device__ __forceinline__ float bf2f(ushort u) {
    union { unsigned u; float f; } v; v.u = (unsigned)u << 16;
    return v.f;
}

// ---------------- fused front: transpose | count | weight-prep ----------------
// blocks [0,8192): transpose f (B,C,N) f32 -> fT (B,N,C) bf16
// blocks [8192,10240): degree count by target
// blocks [10240,10304): W1/W2 -> MFMA B-frag order bf16; Sigma = L L^T
__global__ void k_front(const float* __restrict__ f, ushort* __restrict__ fT,
                        const int2* __restrict__ ei2, int* __restrict__ deg,
                        const float* __restrict__ W1, const float* __restrict__ W2,
                        const float* __restrict__ L, ushort* __restrict__ W1p,
                        ushort* __restrict__ W2p, float* __restrict__ Sig) {
    __shared__ float tile[32][33];
    int bid = blockIdx.x, tid = threadIdx.x;  // 256 threads
    if (bid < 8192) {
        int bx = bid & 511, by = (bid >> 9) & 3, b = bid >> 11;
        int n0 = bx * 32, c0 = by * 32;
        const float* fb = f + (size_t)b * C * N;
        ushort* fTb = fT + (size_t)b * N * C;
        int tx = tid & 31, ty = tid >> 5;
        #pragma unroll
        for (int i = 0; i < 32; i += 8)
            tile[ty + i][tx] = fb[(size_t)(c0 + ty + i) * N + n0 + tx];
        __syncthreads();
        #pragma unroll
        for (int i = 0; i < 32; i += 8)
            fTb[(size_t)(n0 + ty + i) * C + c0 + tx] = f2bf(tile[tx][ty + i]);
    } else if (bid < 10240) {
        int idx = (bid - 8192) * 256 + tid;  // 0..B*E-1
        int b = idx >> 17;
        int tgt = ei2[idx].y;
        atomicAdd(&deg[b * N + tgt], 1);
    } else {
        int gid = (bid - 10240) * 256 + tid;  // 0..16383
        for (int i = gid; i < 8 * 12 * 64 * 8; i += 64 * 256) {
            int j = i & 7, l = (i >> 3) & 63, t = (i >> 9) % 12, nt = (i >> 9) / 12;
            int n = nt * 16 + (l & 15);
            int k = t * 32 + ((l >> 4) & 3) * 8 + j;
            W1p[i] = f2bf(W1[n * K1 + k]);
        }
        {
            int i = gid;  // 16384 elements, one per thread
            int j = i & 7, l = (i >> 3) & 63, t = (i >> 9) % 4, nt = (i >> 9) / 4;
            int n = nt * 16 + (l & 15);
            int k = t * 32 + ((l >> 4) & 3) * 8 + j;
            W2p[i] = f2bf(W2[n * MID + k]);
        }
        if (gid < 9) {
            int i = gid / 3, j = gid % 3;
            Sig[gid] = L[i * 3 + 0] * L[j * 3 + 0] + L[i * 3 + 1] * L[j * 3 + 1] +
                       L[i * 3 + 2] * L[j * 3 + 2];
        }
    }
}

// ---------------- hierarchical exclusive scan over 65536 ints ----------------
__global__ void k_scan1(const int4* __restrict__ degv, int* __restrict__ rowptr,
                        int* __restrict__ bsum) {
    __shared__ int s[256];
    int blk = blockIdx.x, t = threadIdx.x;
    int4 d = degv[blk * 256 + t];
    s[t] = d.x + d.y + d.z + d.w;
    __syncthreads();
    for (int off = 1; off < 256; off <<= 1) {
        int v = s[t];
        int u = (t >= off) ? s[t - off] : 0;
        __syncthreads();
        s[t] = v + u;
        __syncthreads();
    }
    int excl = (t == 0) ? 0 : s[t - 1];
    if (t == 255) bsum[blk] = s[255];
    int4 w;
    w.x = excl;
    w.y = excl + d.x;
    w.z = w.y + d.y;
    w.w = w.z + d.z;
    ((int4*)rowptr)[blk * 256 + t] = w;
}

__global__ void k_scan2(int* __restrict__ bsum, int* __restrict__ rowptr) {
    __shared__ int s[64];
    int t = threadIdx.x;  // 64
    s[t] = bsum[t];
    __syncthreads();
    for (int off = 1; off < 64; off <<= 1) {
        int v = s[t];
        int u = (t >= off) ? s[t - off] : 0;
        __syncthreads();
        s[t] = v + u;
        __syncthreads();
    }
    bsum[t] = (t == 0) ? 0 : s[t - 1];
    if (t == 63) rowptr[B * N] = s[63];
}

__global__ void k_scan3(int4* __restrict__ rowv, const int* __restrict__ bsum) {
    int i = blockIdx.x * 256 + threadIdx.x;  // 0..16383 (int4 index)
    int add = bsum[i >> 8];                  // 256 int4 per scan1 block
    int4 v = rowv[i];
    v.x += add; v.y += add; v.z += add; v.w += add;
    rowv[i] = v;
}

// ---------------- CSR fill pass 1: scatter edge id (4B) ----------------
__global__ void k_fill_perm(const int2* __restrict__ ei2,
                            const int* __restrict__ rowptr,
                            int* __restrict__ cursor, int* __restrict__ perm) {
    int idx = blockIdx.x * 256 + threadIdx.x;
    int b = idx >> 17;
    int tgt = ei2[idx].y;
    int bn = b * N + tgt;
    int pos = atomicAdd(&cursor[bn], 1);
    perm[rowptr[bn] + pos] = idx;
}

// ---------------- CSR fill pass 2: coalesced expand (egwp, ka2) ----------------
__global__ void k_fill_expand(const int* __restrict__ perm,
                              const int2* __restrict__ ei2,
                              const float* __restrict__ egw,
                              const float* __restrict__ nodes,
                              const float* __restrict__ nw,
                              const float* __restrict__ Sig,
                              const float* __restrict__ cb,
                              float4* __restrict__ egwp, float2* __restrict__ ka2) {
    int o = blockIdx.x * 256 + threadIdx.x;
    int idx = perm[o];
    int b = idx >> 17;
    int2 e = ei2[idx];
    int src = e.x, tgt = e.y;
    const float* w = egw + (size_t)idx * ND;
    egwp[o] = make_float4(w[0], w[1], w[2], __int_as_float(src));
    const float* ns = nodes + ((size_t)b * N + src) * ND;
    const float* nt = nodes + ((size_t)b * N + tgt) * ND;
    float d0 = ns[0] - nt[0], d1 = ns[1] - nt[1], d2 = ns[2] - nt[2];
    float q = d0 * (Sig[0] * d0 + Sig[1] * d1 + Sig[2] * d2) +
              d1 * (Sig[3] * d0 + Sig[4] * d1 + Sig[5] * d2) +
              d2 * (Sig[6] * d0 + Sig[7] * d1 + Sig[8] * d2) +
              d0 * cb[0] + d1 * cb[1] + d2 * cb[2];
    ka2[o] = make_float2(nw[(size_t)b * N + src] * expf(-q), __int_as_float(src));
}

// Per-edge gather FMA (8 channels/lane): acc_d += f_src * w_d ; sw_d += w_d.
// (f_tgt folded in at the end: g = acc - f_tgt * sw)
#define GEDGE(W, U)                                                            \
    {                                                                          \
        sw0 += W.x; sw1 += W.y; sw2 += W.z;                                    \
        _Pragma("unroll") for (int u = 0; u < 8; ++u) {                        \
            float fv = bf2f((ushort)U[u]);                                     \
            a0[u] = fmaf(fv, W.x, a0[u]);                                      \
            a1[u] = fmaf(fv, W.y, a1[u]);                                      \
            a2[u] = fmaf(fv, W.z, a2[u]);                                      \
        }                                                                      \
    }

// ---------------- fused gradient gather (VALU) + pointwise MLP (MFMA) --------
// Gather: 32 slots x 16 lanes; lane = 8 channels (ushort8 = 16B loads); one
// node per slot (serial chain = deg/2 rounds at unroll-2, half the loads of
// the 32-lane/8B layout). MFMA: 8 waves = 2 mtiles x 4 nt-pairs (unchanged).
__global__ __launch_bounds__(512, 5) void k_grad_mlp(
    const ushort* __restrict__ fT, const int* __restrict__ rowptr,
    const float4* __restrict__ egwp, const ushort* __restrict__ W1p,
    const float* __restrict__ b1, const ushort* __restrict__ W2p,
    const float* __restrict__ b2, ushort* __restrict__ fo) {
    __shared__ ushort g_s[NT][K1P];  // 25088 B
    int tid = threadIdx.x;
    int n0 = blockIdx.x * NT;  // flat node over B*N

    {  // ---- gather phase ----
        int cg = tid & 15, s = tid >> 4;  // 16 channel-groups x 32 node slots
        int cg8 = cg * 8;
        int n = n0 + s;
        const ushort* fTb = fT + (size_t)(n >> 14) * N * C;  // batch base
        ushort8v ftr = *(const ushort8v*)(fT + (size_t)n * C + cg8);
        int base = rowptr[n], cnt = rowptr[n + 1] - base;
        float a0[8], a1[8], a2[8];
        #pragma unroll
        for (int u = 0; u < 8; ++u) { a0[u] = 0.f; a1[u] = 0.f; a2[u] = 0.f; }
        float sw0 = 0.f, sw1 = 0.f, sw2 = 0.f;
        int i = 0;
        for (; i + 2 <= cnt; i += 2) {
            float4 w0 = egwp[base + i];
            float4 w1 = egwp[base + i + 1];
            ushort8v u0 = *(const ushort8v*)(fTb + (size_t)__float_as_int(w0.w) * C + cg8);
            ushort8v u1 = *(const ushort8v*)(fTb + (size_t)__float_as_int(w1.w) * C + cg8);
            GEDGE(w0, u0);
            GEDGE(w1, u1);
        }
        if (i < cnt) {
            float4 w0 = egwp[base + i];
            ushort8v u0 = *(const ushort8v*)(fTb + (size_t)__float_as_int(w0.w) * C + cg8);
            GEDGE(w0, u0);
        }
        // g[k], k = c*3+d, c = 8cg+u -> k = 24cg+3u+d: 24 contiguous bf16
        unsigned p[12];
        #pragma unroll
        for (int u = 0; u < 4; ++u) {  // pairs of channels 2u, 2u+1
            float ge0 = a0[2 * u] - bf2f((ushort)ftr[2 * u]) * sw0;
            float ge1 = a1[2 * u] - bf2f((ushort)ftr[2 * u]) * sw1;
            float ge2 = a2[2 * u] - bf2f((ushort)ftr[2 * u]) * sw2;
            float go0 = a0[2 * u + 1] - bf2f((ushort)ftr[2 * u + 1]) * sw0;
            float go1 = a1[2 * u + 1] - bf2f((ushort)ftr[2 * u + 1]) * sw1;
            float go2 = a2[2 * u + 1] - bf2f((ushort)ftr[2 * u + 1]) * sw2;
            p[3 * u + 0] = (unsigned)f2bf(ge0) | ((unsigned)f2bf(ge1) << 16);
            p[3 * u + 1] = (unsigned)f2bf(ge2) | ((unsigned)f2bf(go0) << 16);
            p[3 * u + 2] = (unsigned)f2bf(go1) | ((unsigned)f2bf(go2) << 16);
        }
        uint4* dst = (uint4*)&g_s[s][cg * 24];  // byte offset 48*cg: 16B aligned
        dst[0] = make_uint4(p[0], p[1], p[2], p[3]);
        dst[1] = make_uint4(p[4], p[5], p[6], p[7]);
        dst[2] = make_uint4(p[8], p[9], p[10], p[11]);
    }
    __syncthreads();

    // ---- MFMA phase: 8 waves = 2 mtiles x 4 nt-pairs ----
    int wv = tid >> 6, ln = tid & 63, lr = ln & 15, lh = ln >> 4;
    int mt = wv & 1, nh = wv >> 1;
    bf16x8 a[12];  // A-frags for this wave's 16-node mtile, all K
    {
        const ushort* grow = &g_s[mt * 16 + lr][0];
        #pragma unroll
        for (int t = 0; t < 12; ++t)
            a[t] = *(const bf16x8*)(grow + t * 32 + lh * 8);
    }
    __syncthreads();  // all A-reads done before h_s (aliasing g_s) is written

    ushort(*h_s)[136] = (ushort(*)[136]) & g_s[0][0];  // 8704 B alias
    const bf16x8* W1f = (const bf16x8*)W1p;
    #pragma unroll
    for (int q = 0; q < 2; ++q) {
        int nt = nh * 2 + q;
        float bb = b1[nt * 16 + lr];
        f32x4 c = {bb, bb, bb, bb};
        #pragma unroll
        for (int t = 0; t < 12; ++t)
            c = __builtin_amdgcn_mfma_f32_16x16x32_bf16(
                a[t], W1f[(nt * 12 + t) * 64 + ln], c, 0, 0, 0);
        #pragma unroll
        for (int r = 0; r < 4; ++r) {
            float x = c[r];
            x = 0.5f * x * (1.0f + erff(x * 0.70710678118654752f));
            h_s[mt * 16 + lh * 4 + r][nt * 16 + lr] = f2bf(x);  // row=node, col=mid
        }
    }
    __syncthreads();  // all nt-pairs of h complete

    bf16x8 a2[4];
    {
        const ushort* hrow = &h_s[mt * 16 + lr][0];
        #pragma unroll
        for (int t = 0; t < 4; ++t)
            a2[t] = *(const bf16x8*)(hrow + t * 32 + lh * 8);
    }
    const bf16x8* W2f = (const bf16x8*)W2p;
    #pragma unroll
    for (int q = 0; q < 2; ++q) {
        int nt = nh * 2 + q;
        float bb = b2[nt * 16 + lr];
        f32x4 c = {bb, bb, bb, bb};
        #pragma unroll
        for (int t = 0; t < 4; ++t)
            c = __builtin_amdgcn_mfma_f32_16x16x32_bf16(
                a2[t], W2f[(nt * 4 + t) * 64 + ln], c, 0, 0, 0);
        #pragma unroll
        for (int r = 0; r < 4; ++r)
            fo[(size_t)(n0 + mt * 16 + lh * 4 + r) * OUT + nt * 16 + lr] = f2bf(c[r]);
    }
}

#define AGG8(K, U)                                                             \
    {                                                                          \
        den += K.x;                                                            \
        _Pragma("unroll") for (int u = 0; u < 8; ++u)                          \
            o8[u] = fmaf(bf2f((ushort)U[u]), K.x, o8[u]);                      \
    }

// ---------------- edge aggregation (CSR gather) + normalize + fused transpose ----
// 32 slots x 16 lanes x ushort8 (16B fo-row loads); 64 nodes/block, 2/slot.
__global__ __launch_bounds__(512, 5) void k_agg_t(const ushort* __restrict__ fo,
                                                  const float* __restrict__ nw,
                                                  const int* __restrict__ rowptr,
                                                  const float2* __restrict__ ka2,
                                                  float* __restrict__ out) {
    __shared__ float t[OUT][65];
    int tid = threadIdx.x;
    int cg = tid & 15, s = tid >> 4;  // 16 channel-groups x 32 node slots
    int cg8 = cg * 8;
    int n0 = blockIdx.x * 64;         // flat node over B*N
    int b = n0 >> 14, ncol0 = n0 & (N - 1);
    const ushort* fob = fo + (size_t)b * N * OUT;
    #pragma unroll
    for (int g = 0; g < 2; ++g) {
        int nl = g * 32 + s;
        int n = n0 + nl;
        int base = rowptr[n], cnt = rowptr[n + 1] - base;
        float o8[8];
        #pragma unroll
        for (int u = 0; u < 8; ++u) o8[u] = 0.f;
        float den = 0.f;
        int i = 0;
        for (; i + 4 <= cnt; i += 4) {
            float2 k0 = ka2[base + i];
            float2 k1 = ka2[base + i + 1];
            float2 k2 = ka2[base + i + 2];
            float2 k3 = ka2[base + i + 3];
            ushort8v u0 = *(const ushort8v*)(fob + (size_t)__float_as_int(k0.y) * OUT + cg8);
            ushort8v u1 = *(const ushort8v*)(fob + (size_t)__float_as_int(k1.y) * OUT + cg8);
            ushort8v u2 = *(const ushort8v*)(fob + (size_t)__float_as_int(k2.y) * OUT + cg8);
            ushort8v u3 = *(const ushort8v*)(fob + (size_t)__float_as_int(k3.y) * OUT + cg8);
            AGG8(k0, u0);
            AGG8(k1, u1);
            AGG8(k2, u2);
            AGG8(k3, u3);
        }
        for (; i < cnt; ++i) {
            float2 k0 = ka2[base + i];
            ushort8v u0 = *(const ushort8v*)(fob + (size_t)__float_as_int(k0.y) * OUT + cg8);
            AGG8(k0, u0);
        }
        float wn = nw[n];  // self edge: d=0 -> kern = nw[n]
        ushort8v uf = *(const ushort8v*)(fo + (size_t)n * OUT + cg8);
        float inv = 1.f / (den + wn);
        #pragma unroll
        for (int u = 0; u < 8; ++u)
            t[cg8 + u][nl] = (o8[u] + bf2f((ushort)uf[u]) * wn) * inv;
    }
    __syncthreads();
    #pragma unroll
    for (int i = 0; i < 16; ++i) {
        int idx = tid + i * 512;
        int o = idx >> 6, nl = idx & 63;  // nl fastest -> coalesced writes
        out[((size_t)b * OUT + o) * N + ncol0 + nl] = t[o][nl];
    }
}

extern "C" void kernel_launch(void* const* d_in, const int* in_sizes, int n_in,
                              void* d_out, int out_size, void* d_ws, size_t ws_size,
                              hipStream_t stream) {
    const float* f     = (const float*)d_in[0];
    const float* nodes = (const float*)d_in[1];
    const float* nw    = (const float*)d_in[2];
    const int*   ei    = (const int*)d_in[3];
    const float* egw   = (const float*)d_in[4];
    const float* W1    = (const float*)d_in[5];
    const float* b1    = (const float*)d_in[6];
    const float* W2    = (const float*)d_in[7];
    const float* b2    = (const float*)d_in[8];
    const float* L     = (const float*)d_in[9];
    const float* cb    = (const float*)d_in[10];
    float* out = (float*)d_out;

    char* ws = (char*)d_ws;
    auto alloc = [&](size_t bytes) {
        void* p = ws;
        ws += (bytes + 255) & ~(size_t)255;
        return p;
    };
    ushort* fT     = (ushort*)alloc((size_t)B * N * C * 2);
    ushort* fo     = (ushort*)alloc((size_t)B * N * OUT * 2);
    ushort* W1p    = (ushort*)alloc((size_t)MID * K1 * 2);
    ushort* W2p    = (ushort*)alloc((size_t)OUT * MID * 2);
    float*  Sig    = (float*)alloc(16 * 4);
    int*    deg    = (int*)alloc((size_t)B * N * 4);   // contiguous with cursor:
    int*    cursor = (int*)alloc((size_t)B * N * 4);   // one 512KB memset covers both
    int*    rowptr = (int*)alloc(((size_t)B * N + 4) * 4);
    int*    bsum   = (int*)alloc(64 * 4);
    int*    perm   = (int*)alloc((size_t)B * E * 4);
    float4* egwp   = (float4*)alloc((size_t)B * E * 16);
    float2* ka2    = (float2*)alloc((size_t)B * E * 8);

    hipMemsetAsync(deg, 0, (size_t)B * N * 4 * 2, stream);  // deg + cursor

    k_front<<<10304, 256, 0, stream>>>(f, fT, (const int2*)ei, deg, W1, W2, L,
                                       W1p, W2p, Sig);
    k_scan1<<<64, 256, 0, stream>>>((const int4*)deg, rowptr, bsum);
    k_scan2<<<1, 64, 0, stream>>>(bsum, rowptr);
    k_scan3<<<64, 256, 0, stream>>>((int4*)rowptr, bsum);
    k_fill_perm<<<(B * E) / 256, 256, 0, stream>>>((const int2*)ei, rowptr, cursor,
                                                   perm);
    k_fill_expand<<<(B * E) / 256, 256, 0, stream>>>(perm, (const int2*)ei, egw,
                                                     nodes, nw, Sig, cb, egwp, ka2);
    k_grad_mlp<<<(B * N) / NT, 512, 0, stream>>>(fT, rowptr, egwp, W1p, b1, W2p,
                                                 b2, fo);
    k_agg_t<<<(B * N) / 64, 512, 0, stream>>>(fo, nw, rowptr, ka2, out);
}